// Round 1
// baseline (2136.648 us; speedup 1.0000x reference)
//
#include <hip/hip_runtime.h>
#include <math.h>

#define B_ 32
#define N_ 1024
#define C_ 384
#define H_ 1024
#define NRES 20
#define NTAB 21
#define M_TOTAL (B_*N_)   // 32768
#define CHUNK 8192

#define TM 64
#define TN 64
#define TK 16

// ---------------- LN row stats: one wave per row ----------------
__global__ __launch_bounds__(256) void ln_stats_kernel(const float* __restrict__ act,
                                                       float* __restrict__ mu_out,
                                                       float* __restrict__ rstd_out) {
    int wave = threadIdx.x >> 6;
    int lane = threadIdx.x & 63;
    int row  = blockIdx.x * 4 + wave;
    const float* x = act + (size_t)row * C_;
    float v[6];
    float s = 0.f;
#pragma unroll
    for (int i = 0; i < 6; i++) { v[i] = x[lane + i*64]; s += v[i]; }
#pragma unroll
    for (int off = 32; off > 0; off >>= 1) s += __shfl_xor(s, off, 64);
    float mu = s * (1.0f/384.0f);
    float vs = 0.f;
#pragma unroll
    for (int i = 0; i < 6; i++) { float d = v[i]-mu; vs += d*d; }
#pragma unroll
    for (int off = 32; off > 0; off >>= 1) vs += __shfl_xor(vs, off, 64);
    float var = vs * (1.0f/384.0f);
    if (lane == 0) { mu_out[row] = mu; rstd_out[row] = 1.0f / sqrtf(var + 1e-5f); }
}

// ---------------- generic fp32 tiled GEMM, optional fused LN on A, bias+relu epilogue ----
// A: M x K row-major, B: K x N row-major, C: M x N row-major.
// M multiple of 64, K multiple of 16. N may be < tile (guarded).
__global__ __launch_bounds__(256) void gemm_kernel(
    const float* __restrict__ A, const float* __restrict__ Bm,
    const float* __restrict__ bias, float* __restrict__ C,
    int M, int Nn, int K,
    const float* __restrict__ mu, const float* __restrict__ rstd,
    const float* __restrict__ lng, const float* __restrict__ lnb,
    int do_relu)
{
    __shared__ float As[TK][TM+4];
    __shared__ float Bs[TK][TN];
    int tid = threadIdx.x;
    int tm = tid >> 4, tn = tid & 15;
    int m0 = blockIdx.y * TM;
    int n0 = blockIdx.x * TN;
    float acc[4][4] = {};
    int lk = tid & 15;      // k for A-load
    int lm = tid >> 4;      // row base for A-load
    int bn = tid & 63;      // col for B-load
    int bk = tid >> 6;      // k base for B-load

    for (int k0 = 0; k0 < K; k0 += TK) {
#pragma unroll
        for (int r = 0; r < 4; r++) {
            int row = m0 + lm + r*16;
            int kk  = k0 + lk;
            float v = A[(size_t)row * K + kk];
            if (mu) v = (v - mu[row]) * rstd[row] * lng[kk] + lnb[kk];
            As[lk][lm + r*16] = v;
        }
#pragma unroll
        for (int r = 0; r < 4; r++) {
            int kk  = k0 + bk + r*4;
            int col = n0 + bn;
            float v = (col < Nn) ? Bm[(size_t)kk * Nn + col] : 0.f;
            Bs[bk + r*4][bn] = v;
        }
        __syncthreads();
#pragma unroll
        for (int k = 0; k < TK; k++) {
            float a[4], b[4];
#pragma unroll
            for (int i = 0; i < 4; i++) a[i] = As[k][tm*4+i];
#pragma unroll
            for (int j = 0; j < 4; j++) b[j] = Bs[k][tn*4+j];
#pragma unroll
            for (int i = 0; i < 4; i++)
#pragma unroll
                for (int j = 0; j < 4; j++)
                    acc[i][j] = fmaf(a[i], b[j], acc[i][j]);
        }
        __syncthreads();
    }
#pragma unroll
    for (int i = 0; i < 4; i++) {
        int row = m0 + tm*4 + i;
#pragma unroll
        for (int j = 0; j < 4; j++) {
            int col = n0 + tn*4 + j;
            if (col < Nn) {
                float v = acc[i][j] + bias[col];
                if (do_relu) v = fmaxf(v, 0.f);
                C[(size_t)row * Nn + col] = v;
            }
        }
    }
}

// ---------------- argmax + fixed-mask merge ----------------
__global__ __launch_bounds__(256) void argmax_kernel(const float* __restrict__ logits,
                                                     const int* __restrict__ fixed_mask,
                                                     const int* __restrict__ seq_t,
                                                     float* __restrict__ seq_out,
                                                     int* __restrict__ seq_int,
                                                     int m0) {
    int row = m0 + blockIdx.x * blockDim.x + threadIdx.x;
    const float* l = logits + (size_t)row * NRES;
    float best = l[0]; int bi = 0;
#pragma unroll
    for (int j = 1; j < NRES; j++) { float v = l[j]; if (v > best) { best = v; bi = j; } }
    int fm = fixed_mask[row];
    int s = fm ? seq_t[row] : bi;
    seq_int[row] = s;
    seq_out[row] = (float)s;
}

// ---------------- geometry: one thread per (b,n) ----------------
__global__ __launch_bounds__(128) void geom_kernel(
    const float* __restrict__ angles, const float* __restrict__ rigids,
    const int* __restrict__ seq0i, const int* __restrict__ residx,
    const float* __restrict__ dframes, const int* __restrict__ gidx,
    const float* __restrict__ a14m, const float* __restrict__ a37m,
    const float* __restrict__ litp,
    float* __restrict__ out_pred, float* __restrict__ out_final,
    float* __restrict__ out_m14, float* __restrict__ out_m37)
{
    __shared__ float sdf[NTAB*8*16];
    __shared__ int   sgi[NTAB*14];
    __shared__ float sm14[NTAB*14];
    __shared__ float sm37[NTAB*37];
    __shared__ float slit[NTAB*14*3];
    __shared__ float predL[128][43];   // 43 stride: odd -> 2-way max bank aliasing

    for (int i = threadIdx.x; i < NTAB*128; i += 128) sdf[i] = dframes[i];
    for (int i = threadIdx.x; i < NTAB*14; i += 128) { sgi[i] = gidx[i]; sm14[i] = a14m[i]; }
    for (int i = threadIdx.x; i < NTAB*37; i += 128) sm37[i] = a37m[i];
    for (int i = threadIdx.x; i < NTAB*42; i += 128) slit[i] = litp[i];
    __syncthreads();

    int p = blockIdx.x * 128 + threadIdx.x;
    int s = seq0i[p];

    const float* rg = rigids + (size_t)p * 7;
    float qw = rg[0], qx = rg[1], qy = rg[2], qz = rg[3];
    float tbx = rg[4], tby = rg[5], tbz = rg[6];
    float qn = 1.0f / sqrtf(qw*qw + qx*qx + qy*qy + qz*qz + 1e-8f);
    qw *= qn; qx *= qn; qy *= qn; qz *= qn;
    float rb[9];
    rb[0] = 1.f - 2.f*(qy*qy + qz*qz); rb[1] = 2.f*(qx*qy - qw*qz); rb[2] = 2.f*(qx*qz + qw*qy);
    rb[3] = 2.f*(qx*qy + qw*qz); rb[4] = 1.f - 2.f*(qx*qx + qz*qz); rb[5] = 2.f*(qy*qz - qw*qx);
    rb[6] = 2.f*(qx*qz - qw*qy); rb[7] = 2.f*(qy*qz + qw*qx); rb[8] = 1.f - 2.f*(qx*qx + qy*qy);

    float fr[8][9], ft[8][3];
    const float* ang = angles + (size_t)p * 14;
#pragma unroll
    for (int g = 0; g < 8; g++) {
        const float* df = &sdf[(s*8 + g)*16];
        float c, sn;
        if (g == 0) { c = 1.f; sn = 0.f; }
        else { sn = ang[(g-1)*2 + 0]; c = ang[(g-1)*2 + 1]; }
#pragma unroll
        for (int i = 0; i < 3; i++) {
            float d0 = df[i*4+0], d1 = df[i*4+1], d2 = df[i*4+2];
            fr[g][i*3+0] = d0;
            fr[g][i*3+1] = d1*c + d2*sn;
            fr[g][i*3+2] = d2*c - d1*sn;
            ft[g][i] = df[i*4+3];
        }
    }
    // chain compose for groups 5..7: acc = acc o (fr[g], ft[g])
#pragma unroll
    for (int g = 5; g <= 7; g++) {
        float r[9], t[3];
        const float* r1 = fr[g-1];
        const float* t1 = ft[g-1];
#pragma unroll
        for (int i = 0; i < 3; i++) {
#pragma unroll
            for (int j = 0; j < 3; j++)
                r[i*3+j] = r1[i*3+0]*fr[g][0*3+j] + r1[i*3+1]*fr[g][1*3+j] + r1[i*3+2]*fr[g][2*3+j];
            t[i] = r1[i*3+0]*ft[g][0] + r1[i*3+1]*ft[g][1] + r1[i*3+2]*ft[g][2] + t1[i];
        }
#pragma unroll
        for (int i = 0; i < 9; i++) fr[g][i] = r[i];
#pragma unroll
        for (int i = 0; i < 3; i++) ft[g][i] = t[i];
    }
    // global frames: fr[g] <- rb @ fr[g], ft[g] <- rb @ ft[g] + tb
#pragma unroll
    for (int g = 0; g < 8; g++) {
        float r[9], t[3];
#pragma unroll
        for (int i = 0; i < 3; i++) {
#pragma unroll
            for (int j = 0; j < 3; j++)
                r[i*3+j] = rb[i*3+0]*fr[g][0*3+j] + rb[i*3+1]*fr[g][1*3+j] + rb[i*3+2]*fr[g][2*3+j];
            t[i] = rb[i*3+0]*ft[g][0] + rb[i*3+1]*ft[g][1] + rb[i*3+2]*ft[g][2];
        }
        fr[g][0]=r[0]; fr[g][1]=r[1]; fr[g][2]=r[2];
        fr[g][3]=r[3]; fr[g][4]=r[4]; fr[g][5]=r[5];
        fr[g][6]=r[6]; fr[g][7]=r[7]; fr[g][8]=r[8];
        ft[g][0]=t[0]+tbx; ft[g][1]=t[1]+tby; ft[g][2]=t[2]+tbz;
    }
    // atoms: group-outer loop avoids dynamic register indexing
#pragma unroll
    for (int g = 0; g < 8; g++) {
#pragma unroll
        for (int a = 0; a < 14; a++) {
            if (sgi[s*14 + a] == g) {
                float m  = sm14[s*14 + a];
                float lx = slit[(s*14 + a)*3 + 0];
                float ly = slit[(s*14 + a)*3 + 1];
                float lz = slit[(s*14 + a)*3 + 2];
                float px = (fr[g][0]*lx + fr[g][1]*ly + fr[g][2]*lz + ft[g][0]) * m;
                float py = (fr[g][3]*lx + fr[g][4]*ly + fr[g][5]*lz + ft[g][1]) * m;
                float pz = (fr[g][6]*lx + fr[g][7]*ly + fr[g][8]*lz + ft[g][2]) * m;
                predL[threadIdx.x][a*3+0] = px;
                predL[threadIdx.x][a*3+1] = py;
                predL[threadIdx.x][a*3+2] = pz;
                out_pred[((size_t)p*14 + a)*3 + 0] = px;
                out_pred[((size_t)p*14 + a)*3 + 1] = py;
                out_pred[((size_t)p*14 + a)*3 + 2] = pz;
            }
        }
    }
#pragma unroll
    for (int a = 0; a < 14; a++) out_m14[(size_t)p*14 + a] = sm14[s*14 + a];

    const int* idx = residx + (size_t)p * 37;
#pragma unroll
    for (int a = 0; a < 37; a++) {
        int id = idx[a];
        out_final[((size_t)p*37 + a)*3 + 0] = predL[threadIdx.x][id*3+0];
        out_final[((size_t)p*37 + a)*3 + 1] = predL[threadIdx.x][id*3+1];
        out_final[((size_t)p*37 + a)*3 + 2] = predL[threadIdx.x][id*3+2];
        out_m37[(size_t)p*37 + a] = sm37[s*37 + a];
    }
}

extern "C" void kernel_launch(void* const* d_in, const int* in_sizes, int n_in,
                              void* d_out, int out_size, void* d_ws, size_t ws_size,
                              hipStream_t stream) {
    const float* act        = (const float*)d_in[0];
    const float* angles     = (const float*)d_in[1];
    const float* rigids     = (const float*)d_in[2];
    const int*   fixed_mask = (const int*)d_in[3];
    const int*   seq_t      = (const int*)d_in[4];
    const int*   residx     = (const int*)d_in[5];
    const float* lng        = (const float*)d_in[6];
    const float* lnb        = (const float*)d_in[7];
    const float* w1         = (const float*)d_in[8];
    const float* b1         = (const float*)d_in[9];
    const float* w2         = (const float*)d_in[10];
    const float* b2         = (const float*)d_in[11];
    const float* w3         = (const float*)d_in[12];
    const float* b3         = (const float*)d_in[13];
    const float* dfr        = (const float*)d_in[14];
    const int*   gidx       = (const int*)d_in[15];
    const float* a14m       = (const float*)d_in[16];
    const float* a37m       = (const float*)d_in[17];
    const float* litp       = (const float*)d_in[18];

    float* out        = (float*)d_out;
    float* out_logits = out;
    float* out_seq    = out_logits + (size_t)M_TOTAL * NRES;
    float* out_pred   = out_seq    + (size_t)M_TOTAL;
    float* out_final  = out_pred   + (size_t)M_TOTAL * 42;
    float* out_m14    = out_final  + (size_t)M_TOTAL * 111;
    float* out_m37    = out_m14    + (size_t)M_TOTAL * 14;

    char* wsp = (char*)d_ws;
    int*   seq0i = (int*)wsp;   wsp += (size_t)M_TOTAL * sizeof(int);
    float* mu    = (float*)wsp; wsp += (size_t)M_TOTAL * sizeof(float);
    float* rstd  = (float*)wsp; wsp += (size_t)M_TOTAL * sizeof(float);
    float* H1    = (float*)wsp; wsp += (size_t)CHUNK * H_ * sizeof(float);
    float* H2    = (float*)wsp;

    ln_stats_kernel<<<M_TOTAL/4, 256, 0, stream>>>(act, mu, rstd);

    for (int c = 0; c < M_TOTAL / CHUNK; c++) {
        int m0 = c * CHUNK;
        dim3 g1(H_/TN, CHUNK/TM);
        gemm_kernel<<<g1, 256, 0, stream>>>(act + (size_t)m0 * C_, w1, b1, H1,
                                            CHUNK, H_, C_, mu + m0, rstd + m0, lng, lnb, 1);
        gemm_kernel<<<g1, 256, 0, stream>>>(H1, w2, b2, H2,
                                            CHUNK, H_, H_, nullptr, nullptr, nullptr, nullptr, 1);
        dim3 g3(1, CHUNK/TM);
        gemm_kernel<<<g3, 256, 0, stream>>>(H2, w3, b3, out_logits + (size_t)m0 * NRES,
                                            CHUNK, NRES, H_, nullptr, nullptr, nullptr, nullptr, 0);
        argmax_kernel<<<CHUNK/256, 256, 0, stream>>>(out_logits, fixed_mask, seq_t,
                                                     out_seq, seq0i, m0);
    }

    geom_kernel<<<M_TOTAL/128, 128, 0, stream>>>(angles, rigids, seq0i, residx,
                                                 dfr, gidx, a14m, a37m, litp,
                                                 out_pred, out_final, out_m14, out_m37);
}

// Round 2
// 1439.481 us; speedup vs baseline: 1.4843x; 1.4843x over previous
//
#include <hip/hip_runtime.h>
#include <math.h>

#define B_ 32
#define N_ 1024
#define C_ 384
#define H_ 1024
#define NRES 20
#define NTAB 21
#define M_TOTAL (B_*N_)   // 32768
#define CHUNK 4096

#define BM 128
#define BN 128
#define BK 32
#define LDK 40   // LDS row stride (elements): keeps 16B alignment for b128 reads

typedef __attribute__((ext_vector_type(8))) short bf16x8;
typedef __attribute__((ext_vector_type(4))) float f32x4;

__device__ inline short bf16_rne(float v) {
    unsigned u = __float_as_uint(v);
    unsigned r = u + 0x7fffu + ((u >> 16) & 1u);
    return (short)(r >> 16);
}
// v ~= hi + lo, each bf16 (RNE). ~16 mantissa bits captured.
__device__ inline void split2(float v, short& h, short& l) {
    unsigned u = __float_as_uint(v);
    unsigned r = (u + 0x7fffu + ((u >> 16) & 1u)) & 0xffff0000u;
    h = (short)(r >> 16);
    l = bf16_rne(v - __uint_as_float(r));
}

// ---------------- LN row stats: one wave per row ----------------
__global__ __launch_bounds__(256) void ln_stats_kernel(const float* __restrict__ act,
                                                       float* __restrict__ mu_out,
                                                       float* __restrict__ rstd_out) {
    int wave = threadIdx.x >> 6;
    int lane = threadIdx.x & 63;
    int row  = blockIdx.x * 4 + wave;
    const float* x = act + (size_t)row * C_;
    float v[6];
    float s = 0.f;
#pragma unroll
    for (int i = 0; i < 6; i++) { v[i] = x[lane + i*64]; s += v[i]; }
#pragma unroll
    for (int off = 32; off > 0; off >>= 1) s += __shfl_xor(s, off, 64);
    float mu = s * (1.0f/384.0f);
    float vs = 0.f;
#pragma unroll
    for (int i = 0; i < 6; i++) { float d = v[i]-mu; vs += d*d; }
#pragma unroll
    for (int off = 32; off > 0; off >>= 1) vs += __shfl_xor(vs, off, 64);
    float var = vs * (1.0f/384.0f);
    if (lane == 0) { mu_out[row] = mu; rstd_out[row] = 1.0f / sqrtf(var + 1e-5f); }
}

// ---------------- weight transpose + split-bf16 convert ----------------
// w: K x N fp32 row-major  ->  th/tl: Npad x K bf16 ("B^T" layout, k contiguous)
__global__ __launch_bounds__(256) void conv_w_kernel(const float* __restrict__ w,
                                                     short* __restrict__ th,
                                                     short* __restrict__ tl,
                                                     int K, int N, int Npad) {
    __shared__ float t[32][33];
    int n0 = blockIdx.x * 32, k0 = blockIdx.y * 32;
    int tx = threadIdx.x & 31, ty = threadIdx.x >> 5;   // ty 0..7
#pragma unroll
    for (int i = ty; i < 32; i += 8) {
        int k = k0 + i, n = n0 + tx;
        t[i][tx] = (n < N) ? w[(size_t)k * N + n] : 0.f;
    }
    __syncthreads();
#pragma unroll
    for (int i = ty; i < 32; i += 8) {
        int n = n0 + i, k = k0 + tx;
        short h, l; split2(t[tx][i], h, l);
        th[(size_t)n * K + k] = h;
        tl[(size_t)n * K + k] = l;
    }
}

// ---------------- split-bf16 MFMA GEMM ----------------
// A: chunkM x K fp32 (optionally LN-fused), BT: Npad x K bf16 split, C: chunkM x ldc fp32
__global__ __launch_bounds__(256) void mfma_gemm(
    const float* __restrict__ A,
    const short* __restrict__ BTh, const short* __restrict__ BTl,
    const float* __restrict__ bias, float* __restrict__ C,
    int K, int ldc, int Nvalid,
    const float* __restrict__ mu, const float* __restrict__ rstd,
    const float* __restrict__ lng, const float* __restrict__ lnb,
    int do_relu)
{
    __shared__ short Ah[BM][LDK], Al[BM][LDK];
    __shared__ short Bh[BN][LDK], Bl[BN][LDK];
    int tid = threadIdx.x;
    int m0 = blockIdx.y * BM;
    int n0 = blockIdx.x * BN;
    int lane = tid & 63, wv = tid >> 6;
    int wm = (wv & 1) * 64, wn = (wv >> 1) * 64;
    int fm = lane & 15, kg = lane >> 4;

    f32x4 acc[4][4] = {};

    int ar = tid >> 3;          // 0..31
    int ak = (tid & 7) * 4;     // 0,4,...,28
    int br = tid >> 2;          // 0..63
    int bk8 = (tid & 3) * 8;    // 0,8,16,24

    for (int k0 = 0; k0 < K; k0 += BK) {
        // ---- stage A (fp32 -> split bf16), 128x32 ----
#pragma unroll
        for (int p = 0; p < 4; p++) {
            int row = m0 + ar + p * 32;
            float4 v = *(const float4*)&A[(size_t)row * K + k0 + ak];
            if (mu) {
                float m_ = mu[row], rs = rstd[row];
                float4 g = *(const float4*)&lng[k0 + ak];
                float4 b = *(const float4*)&lnb[k0 + ak];
                v.x = (v.x - m_) * rs * g.x + b.x;
                v.y = (v.y - m_) * rs * g.y + b.y;
                v.z = (v.z - m_) * rs * g.z + b.z;
                v.w = (v.w - m_) * rs * g.w + b.w;
            }
            short4 h4, l4;
            split2(v.x, h4.x, l4.x);
            split2(v.y, h4.y, l4.y);
            split2(v.z, h4.z, l4.z);
            split2(v.w, h4.w, l4.w);
            *(short4*)&Ah[ar + p*32][ak] = h4;
            *(short4*)&Al[ar + p*32][ak] = l4;
        }
        // ---- stage B (pre-split bf16, transposed), 128x32 ----
#pragma unroll
        for (int p = 0; p < 2; p++) {
            int row = n0 + br + p * 64;
            int4 vh = *(const int4*)&BTh[(size_t)row * K + k0 + bk8];
            int4 vl = *(const int4*)&BTl[(size_t)row * K + k0 + bk8];
            *(int4*)&Bh[br + p*64][bk8] = vh;
            *(int4*)&Bl[br + p*64][bk8] = vl;
        }
        __syncthreads();

        bf16x8 a_h[4], a_l[4], b_h[4], b_l[4];
#pragma unroll
        for (int i = 0; i < 4; i++) {
            a_h[i] = *(bf16x8*)&Ah[wm + i*16 + fm][kg*8];
            a_l[i] = *(bf16x8*)&Al[wm + i*16 + fm][kg*8];
            b_h[i] = *(bf16x8*)&Bh[wn + i*16 + fm][kg*8];
            b_l[i] = *(bf16x8*)&Bl[wn + i*16 + fm][kg*8];
        }
#pragma unroll
        for (int i = 0; i < 4; i++)
#pragma unroll
            for (int j = 0; j < 4; j++) {
                f32x4 c = acc[i][j];
                c = __builtin_amdgcn_mfma_f32_16x16x32_bf16(a_l[i], b_h[j], c, 0, 0, 0);
                c = __builtin_amdgcn_mfma_f32_16x16x32_bf16(a_h[i], b_l[j], c, 0, 0, 0);
                c = __builtin_amdgcn_mfma_f32_16x16x32_bf16(a_h[i], b_h[j], c, 0, 0, 0);
                acc[i][j] = c;
            }
        __syncthreads();
    }

    // ---- epilogue: bias (+relu), fp32 store ----
#pragma unroll
    for (int i = 0; i < 4; i++)
#pragma unroll
        for (int j = 0; j < 4; j++) {
            int col = n0 + wn + j*16 + fm;
            if (col < Nvalid) {
                float bs = bias[col];
#pragma unroll
                for (int r = 0; r < 4; r++) {
                    int row = m0 + wm + i*16 + kg*4 + r;
                    float v = acc[i][j][r] + bs;
                    if (do_relu) v = fmaxf(v, 0.f);
                    C[(size_t)row * ldc + col] = v;
                }
            }
        }
}

// ---------------- argmax + fixed-mask merge ----------------
__global__ __launch_bounds__(256) void argmax_kernel(const float* __restrict__ logits,
                                                     const int* __restrict__ fixed_mask,
                                                     const int* __restrict__ seq_t,
                                                     float* __restrict__ seq_out,
                                                     int* __restrict__ seq_int,
                                                     int m0) {
    int row = m0 + blockIdx.x * blockDim.x + threadIdx.x;
    const float* l = logits + (size_t)row * NRES;
    float best = l[0]; int bi = 0;
#pragma unroll
    for (int j = 1; j < NRES; j++) { float v = l[j]; if (v > best) { best = v; bi = j; } }
    int fm = fixed_mask[row];
    int s = fm ? seq_t[row] : bi;
    seq_int[row] = s;
    seq_out[row] = (float)s;
}

// ---------------- geometry: one thread per (b,n) ----------------
__global__ __launch_bounds__(128) void geom_kernel(
    const float* __restrict__ angles, const float* __restrict__ rigids,
    const int* __restrict__ seq0i, const int* __restrict__ residx,
    const float* __restrict__ dframes, const int* __restrict__ gidx,
    const float* __restrict__ a14m, const float* __restrict__ a37m,
    const float* __restrict__ litp,
    float* __restrict__ out_pred, float* __restrict__ out_final,
    float* __restrict__ out_m14, float* __restrict__ out_m37)
{
    __shared__ float sdf[NTAB*8*16];
    __shared__ int   sgi[NTAB*14];
    __shared__ float sm14[NTAB*14];
    __shared__ float sm37[NTAB*37];
    __shared__ float slit[NTAB*14*3];
    __shared__ float predL[128][43];

    for (int i = threadIdx.x; i < NTAB*128; i += 128) sdf[i] = dframes[i];
    for (int i = threadIdx.x; i < NTAB*14; i += 128) { sgi[i] = gidx[i]; sm14[i] = a14m[i]; }
    for (int i = threadIdx.x; i < NTAB*37; i += 128) sm37[i] = a37m[i];
    for (int i = threadIdx.x; i < NTAB*42; i += 128) slit[i] = litp[i];
    __syncthreads();

    int p = blockIdx.x * 128 + threadIdx.x;
    int s = seq0i[p];

    const float* rg = rigids + (size_t)p * 7;
    float qw = rg[0], qx = rg[1], qy = rg[2], qz = rg[3];
    float tbx = rg[4], tby = rg[5], tbz = rg[6];
    float qn = 1.0f / sqrtf(qw*qw + qx*qx + qy*qy + qz*qz + 1e-8f);
    qw *= qn; qx *= qn; qy *= qn; qz *= qn;
    float rb[9];
    rb[0] = 1.f - 2.f*(qy*qy + qz*qz); rb[1] = 2.f*(qx*qy - qw*qz); rb[2] = 2.f*(qx*qz + qw*qy);
    rb[3] = 2.f*(qx*qy + qw*qz); rb[4] = 1.f - 2.f*(qx*qx + qz*qz); rb[5] = 2.f*(qy*qz - qw*qx);
    rb[6] = 2.f*(qx*qz - qw*qy); rb[7] = 2.f*(qy*qz + qw*qx); rb[8] = 1.f - 2.f*(qx*qx + qy*qy);

    float fr[8][9], ft[8][3];
    const float* ang = angles + (size_t)p * 14;
#pragma unroll
    for (int g = 0; g < 8; g++) {
        const float* df = &sdf[(s*8 + g)*16];
        float c, sn;
        if (g == 0) { c = 1.f; sn = 0.f; }
        else { sn = ang[(g-1)*2 + 0]; c = ang[(g-1)*2 + 1]; }
#pragma unroll
        for (int i = 0; i < 3; i++) {
            float d0 = df[i*4+0], d1 = df[i*4+1], d2 = df[i*4+2];
            fr[g][i*3+0] = d0;
            fr[g][i*3+1] = d1*c + d2*sn;
            fr[g][i*3+2] = d2*c - d1*sn;
            ft[g][i] = df[i*4+3];
        }
    }
#pragma unroll
    for (int g = 5; g <= 7; g++) {
        float r[9], t[3];
        const float* r1 = fr[g-1];
        const float* t1 = ft[g-1];
#pragma unroll
        for (int i = 0; i < 3; i++) {
#pragma unroll
            for (int j = 0; j < 3; j++)
                r[i*3+j] = r1[i*3+0]*fr[g][0*3+j] + r1[i*3+1]*fr[g][1*3+j] + r1[i*3+2]*fr[g][2*3+j];
            t[i] = r1[i*3+0]*ft[g][0] + r1[i*3+1]*ft[g][1] + r1[i*3+2]*ft[g][2] + t1[i];
        }
#pragma unroll
        for (int i = 0; i < 9; i++) fr[g][i] = r[i];
#pragma unroll
        for (int i = 0; i < 3; i++) ft[g][i] = t[i];
    }
#pragma unroll
    for (int g = 0; g < 8; g++) {
        float r[9], t[3];
#pragma unroll
        for (int i = 0; i < 3; i++) {
#pragma unroll
            for (int j = 0; j < 3; j++)
                r[i*3+j] = rb[i*3+0]*fr[g][0*3+j] + rb[i*3+1]*fr[g][1*3+j] + rb[i*3+2]*fr[g][2*3+j];
            t[i] = rb[i*3+0]*ft[g][0] + rb[i*3+1]*ft[g][1] + rb[i*3+2]*ft[g][2];
        }
#pragma unroll
        for (int i = 0; i < 9; i++) fr[g][i] = r[i];
        ft[g][0]=t[0]+tbx; ft[g][1]=t[1]+tby; ft[g][2]=t[2]+tbz;
    }
#pragma unroll
    for (int g = 0; g < 8; g++) {
#pragma unroll
        for (int a = 0; a < 14; a++) {
            if (sgi[s*14 + a] == g) {
                float m  = sm14[s*14 + a];
                float lx = slit[(s*14 + a)*3 + 0];
                float ly = slit[(s*14 + a)*3 + 1];
                float lz = slit[(s*14 + a)*3 + 2];
                float px = (fr[g][0]*lx + fr[g][1]*ly + fr[g][2]*lz + ft[g][0]) * m;
                float py = (fr[g][3]*lx + fr[g][4]*ly + fr[g][5]*lz + ft[g][1]) * m;
                float pz = (fr[g][6]*lx + fr[g][7]*ly + fr[g][8]*lz + ft[g][2]) * m;
                predL[threadIdx.x][a*3+0] = px;
                predL[threadIdx.x][a*3+1] = py;
                predL[threadIdx.x][a*3+2] = pz;
                out_pred[((size_t)p*14 + a)*3 + 0] = px;
                out_pred[((size_t)p*14 + a)*3 + 1] = py;
                out_pred[((size_t)p*14 + a)*3 + 2] = pz;
            }
        }
    }
#pragma unroll
    for (int a = 0; a < 14; a++) out_m14[(size_t)p*14 + a] = sm14[s*14 + a];

    const int* idx = residx + (size_t)p * 37;
#pragma unroll
    for (int a = 0; a < 37; a++) {
        int id = idx[a];
        out_final[((size_t)p*37 + a)*3 + 0] = predL[threadIdx.x][id*3+0];
        out_final[((size_t)p*37 + a)*3 + 1] = predL[threadIdx.x][id*3+1];
        out_final[((size_t)p*37 + a)*3 + 2] = predL[threadIdx.x][id*3+2];
        out_m37[(size_t)p*37 + a] = sm37[s*37 + a];
    }
}

extern "C" void kernel_launch(void* const* d_in, const int* in_sizes, int n_in,
                              void* d_out, int out_size, void* d_ws, size_t ws_size,
                              hipStream_t stream) {
    const float* act        = (const float*)d_in[0];
    const float* angles     = (const float*)d_in[1];
    const float* rigids     = (const float*)d_in[2];
    const int*   fixed_mask = (const int*)d_in[3];
    const int*   seq_t      = (const int*)d_in[4];
    const int*   residx     = (const int*)d_in[5];
    const float* lng        = (const float*)d_in[6];
    const float* lnb        = (const float*)d_in[7];
    const float* w1         = (const float*)d_in[8];
    const float* b1         = (const float*)d_in[9];
    const float* w2         = (const float*)d_in[10];
    const float* b2         = (const float*)d_in[11];
    const float* w3         = (const float*)d_in[12];
    const float* b3         = (const float*)d_in[13];
    const float* dfr        = (const float*)d_in[14];
    const int*   gidx       = (const int*)d_in[15];
    const float* a14m       = (const float*)d_in[16];
    const float* a37m       = (const float*)d_in[17];
    const float* litp       = (const float*)d_in[18];

    float* out        = (float*)d_out;
    float* out_logits = out;
    float* out_seq    = out_logits + (size_t)M_TOTAL * NRES;
    float* out_pred   = out_seq    + (size_t)M_TOTAL;
    float* out_final  = out_pred   + (size_t)M_TOTAL * 42;
    float* out_m14    = out_final  + (size_t)M_TOTAL * 111;
    float* out_m37    = out_m14    + (size_t)M_TOTAL * 14;

    char* wsp = (char*)d_ws;
    int*   seq0i = (int*)wsp;   wsp += (size_t)M_TOTAL * sizeof(int);
    float* mu    = (float*)wsp; wsp += (size_t)M_TOTAL * sizeof(float);
    float* rstd  = (float*)wsp; wsp += (size_t)M_TOTAL * sizeof(float);
    short* w1h   = (short*)wsp; wsp += (size_t)H_ * C_ * sizeof(short);
    short* w1l   = (short*)wsp; wsp += (size_t)H_ * C_ * sizeof(short);
    short* w2h   = (short*)wsp; wsp += (size_t)H_ * H_ * sizeof(short);
    short* w2l   = (short*)wsp; wsp += (size_t)H_ * H_ * sizeof(short);
    short* w3h   = (short*)wsp; wsp += (size_t)128 * H_ * sizeof(short);
    short* w3l   = (short*)wsp; wsp += (size_t)128 * H_ * sizeof(short);
    float* H1    = (float*)wsp; wsp += (size_t)CHUNK * H_ * sizeof(float);
    float* H2    = (float*)wsp;

    // one-time (per launch) weight conversion: transpose + split-bf16
    conv_w_kernel<<<dim3(H_/32, C_/32), 256, 0, stream>>>(w1, w1h, w1l, C_, H_, H_);
    conv_w_kernel<<<dim3(H_/32, H_/32), 256, 0, stream>>>(w2, w2h, w2l, H_, H_, H_);
    conv_w_kernel<<<dim3(128/32, H_/32), 256, 0, stream>>>(w3, w3h, w3l, H_, NRES, 128);

    ln_stats_kernel<<<M_TOTAL/4, 256, 0, stream>>>(act, mu, rstd);

    for (int c = 0; c < M_TOTAL / CHUNK; c++) {
        int m0 = c * CHUNK;
        dim3 g1(H_/BN, CHUNK/BM);
        // GEMM1: LN(act) @ w1 + b1, relu
        mfma_gemm<<<g1, 256, 0, stream>>>(act + (size_t)m0 * C_, w1h, w1l, b1, H1,
                                          C_, H_, H_, mu + m0, rstd + m0, lng, lnb, 1);
        // GEMM2: H1 @ w2 + b2, relu
        mfma_gemm<<<g1, 256, 0, stream>>>(H1, w2h, w2l, b2, H2,
                                          H_, H_, H_, nullptr, nullptr, nullptr, nullptr, 1);
        // GEMM3: H2 @ w3 + b3 (N=20, padded to 128)
        dim3 g3(1, CHUNK/BM);
        mfma_gemm<<<g3, 256, 0, stream>>>(H2, w3h, w3l, b3, out_logits + (size_t)m0 * NRES,
                                          H_, NRES, NRES, nullptr, nullptr, nullptr, nullptr, 0);
        argmax_kernel<<<CHUNK/256, 256, 0, stream>>>(out_logits, fixed_mask, seq_t,
                                                     out_seq, seq0i, m0);
    }

    geom_kernel<<<M_TOTAL/128, 128, 0, stream>>>(angles, rigids, seq0i, residx,
                                                 dfr, gidx, a14m, a37m, litp,
                                                 out_pred, out_final, out_m14, out_m37);
}

// Round 3
// 1425.892 us; speedup vs baseline: 1.4985x; 1.0095x over previous
//
#include <hip/hip_runtime.h>
#include <math.h>

#define B_ 32
#define N_ 1024
#define C_ 384
#define H_ 1024
#define NRES 20
#define NTAB 21
#define M_TOTAL (B_*N_)   // 32768

#define BM 128
#define BN 128
#define BK 32
#define LDK 40   // LDS row stride (elements): keeps 16B alignment for b128 reads

typedef __attribute__((ext_vector_type(8))) short bf16x8;
typedef __attribute__((ext_vector_type(4))) float f32x4;

__device__ inline short bf16_rne(float v) {
    unsigned u = __float_as_uint(v);
    unsigned r = u + 0x7fffu + ((u >> 16) & 1u);
    return (short)(r >> 16);
}
// v ~= hi + lo, each bf16 (RNE). ~16 mantissa bits captured.
__device__ inline void split2(float v, short& h, short& l) {
    unsigned u = __float_as_uint(v);
    unsigned r = (u + 0x7fffu + ((u >> 16) & 1u)) & 0xffff0000u;
    h = (short)(r >> 16);
    l = bf16_rne(v - __uint_as_float(r));
}

// ---------------- LN row stats: one wave per row ----------------
__global__ __launch_bounds__(256) void ln_stats_kernel(const float* __restrict__ act,
                                                       float* __restrict__ mu_out,
                                                       float* __restrict__ rstd_out) {
    int wave = threadIdx.x >> 6;
    int lane = threadIdx.x & 63;
    int row  = blockIdx.x * 4 + wave;
    const float* x = act + (size_t)row * C_;
    float v[6];
    float s = 0.f;
#pragma unroll
    for (int i = 0; i < 6; i++) { v[i] = x[lane + i*64]; s += v[i]; }
#pragma unroll
    for (int off = 32; off > 0; off >>= 1) s += __shfl_xor(s, off, 64);
    float mu = s * (1.0f/384.0f);
    float vs = 0.f;
#pragma unroll
    for (int i = 0; i < 6; i++) { float d = v[i]-mu; vs += d*d; }
#pragma unroll
    for (int off = 32; off > 0; off >>= 1) vs += __shfl_xor(vs, off, 64);
    float var = vs * (1.0f/384.0f);
    if (lane == 0) { mu_out[row] = mu; rstd_out[row] = 1.0f / sqrtf(var + 1e-5f); }
}

// ---------------- weight transpose + split-bf16 convert ----------------
__global__ __launch_bounds__(256) void conv_w_kernel(const float* __restrict__ w,
                                                     short* __restrict__ th,
                                                     short* __restrict__ tl,
                                                     int K, int N, int Npad) {
    __shared__ float t[32][33];
    int n0 = blockIdx.x * 32, k0 = blockIdx.y * 32;
    int tx = threadIdx.x & 31, ty = threadIdx.x >> 5;
#pragma unroll
    for (int i = ty; i < 32; i += 8) {
        int k = k0 + i, n = n0 + tx;
        t[i][tx] = (n < N) ? w[(size_t)k * N + n] : 0.f;
    }
    __syncthreads();
#pragma unroll
    for (int i = ty; i < 32; i += 8) {
        int n = n0 + i, k = k0 + tx;
        short h, l; split2(t[tx][i], h, l);
        th[(size_t)n * K + k] = h;
        tl[(size_t)n * K + k] = l;
    }
}

// ---------------- split-bf16 MFMA GEMM ----------------
__global__ __launch_bounds__(256) void mfma_gemm(
    const float* __restrict__ A,
    const short* __restrict__ BTh, const short* __restrict__ BTl,
    const float* __restrict__ bias, float* __restrict__ C,
    int K, int ldc, int Nvalid,
    const float* __restrict__ mu, const float* __restrict__ rstd,
    const float* __restrict__ lng, const float* __restrict__ lnb,
    int do_relu)
{
    __shared__ short Ah[BM][LDK], Al[BM][LDK];
    __shared__ short Bh[BN][LDK], Bl[BN][LDK];
    int tid = threadIdx.x;
    int m0 = blockIdx.y * BM;
    int n0 = blockIdx.x * BN;
    int lane = tid & 63, wv = tid >> 6;
    int wm = (wv & 1) * 64, wn = (wv >> 1) * 64;
    int fm = lane & 15, kg = lane >> 4;

    f32x4 acc[4][4] = {};

    int ar = tid >> 3;          // 0..31
    int ak = (tid & 7) * 4;     // 0,4,...,28
    int br = tid >> 2;          // 0..63
    int bk8 = (tid & 3) * 8;    // 0,8,16,24

    for (int k0 = 0; k0 < K; k0 += BK) {
#pragma unroll
        for (int p = 0; p < 4; p++) {
            int row = m0 + ar + p * 32;
            float4 v = *(const float4*)&A[(size_t)row * K + k0 + ak];
            if (mu) {
                float m_ = mu[row], rs = rstd[row];
                float4 g = *(const float4*)&lng[k0 + ak];
                float4 b = *(const float4*)&lnb[k0 + ak];
                v.x = (v.x - m_) * rs * g.x + b.x;
                v.y = (v.y - m_) * rs * g.y + b.y;
                v.z = (v.z - m_) * rs * g.z + b.z;
                v.w = (v.w - m_) * rs * g.w + b.w;
            }
            short4 h4, l4;
            split2(v.x, h4.x, l4.x);
            split2(v.y, h4.y, l4.y);
            split2(v.z, h4.z, l4.z);
            split2(v.w, h4.w, l4.w);
            *(short4*)&Ah[ar + p*32][ak] = h4;
            *(short4*)&Al[ar + p*32][ak] = l4;
        }
#pragma unroll
        for (int p = 0; p < 2; p++) {
            int row = n0 + br + p * 64;
            int4 vh = *(const int4*)&BTh[(size_t)row * K + k0 + bk8];
            int4 vl = *(const int4*)&BTl[(size_t)row * K + k0 + bk8];
            *(int4*)&Bh[br + p*64][bk8] = vh;
            *(int4*)&Bl[br + p*64][bk8] = vl;
        }
        __syncthreads();

        bf16x8 a_h[4], a_l[4], b_h[4], b_l[4];
#pragma unroll
        for (int i = 0; i < 4; i++) {
            a_h[i] = *(bf16x8*)&Ah[wm + i*16 + fm][kg*8];
            a_l[i] = *(bf16x8*)&Al[wm + i*16 + fm][kg*8];
            b_h[i] = *(bf16x8*)&Bh[wn + i*16 + fm][kg*8];
            b_l[i] = *(bf16x8*)&Bl[wn + i*16 + fm][kg*8];
        }
#pragma unroll
        for (int i = 0; i < 4; i++)
#pragma unroll
            for (int j = 0; j < 4; j++) {
                f32x4 c = acc[i][j];
                c = __builtin_amdgcn_mfma_f32_16x16x32_bf16(a_l[i], b_h[j], c, 0, 0, 0);
                c = __builtin_amdgcn_mfma_f32_16x16x32_bf16(a_h[i], b_l[j], c, 0, 0, 0);
                c = __builtin_amdgcn_mfma_f32_16x16x32_bf16(a_h[i], b_h[j], c, 0, 0, 0);
                acc[i][j] = c;
            }
        __syncthreads();
    }

#pragma unroll
    for (int i = 0; i < 4; i++)
#pragma unroll
        for (int j = 0; j < 4; j++) {
            int col = n0 + wn + j*16 + fm;
            if (col < Nvalid) {
                float bs = bias[col];
#pragma unroll
                for (int r = 0; r < 4; r++) {
                    int row = m0 + wm + i*16 + kg*4 + r;
                    float v = acc[i][j][r] + bs;
                    if (do_relu) v = fmaxf(v, 0.f);
                    C[(size_t)row * ldc + col] = v;
                }
            }
        }
}

// ---------------- argmax + fixed-mask merge ----------------
__global__ __launch_bounds__(256) void argmax_kernel(const float* __restrict__ logits,
                                                     const int* __restrict__ fixed_mask,
                                                     const int* __restrict__ seq_t,
                                                     float* __restrict__ seq_out,
                                                     int* __restrict__ seq_int) {
    int row = blockIdx.x * blockDim.x + threadIdx.x;
    const float* l = logits + (size_t)row * NRES;
    float best = l[0]; int bi = 0;
#pragma unroll
    for (int j = 1; j < NRES; j++) { float v = l[j]; if (v > best) { best = v; bi = j; } }
    int fm = fixed_mask[row];
    int s = fm ? seq_t[row] : bi;
    seq_int[row] = s;
    seq_out[row] = (float)s;
}

// ---------------- geometry: one thread per (b,n) ----------------
__global__ __launch_bounds__(128) void geom_kernel(
    const float* __restrict__ angles, const float* __restrict__ rigids,
    const int* __restrict__ seq0i, const int* __restrict__ residx,
    const float* __restrict__ dframes, const int* __restrict__ gidx,
    const float* __restrict__ a14m, const float* __restrict__ a37m,
    const float* __restrict__ litp,
    float* __restrict__ out_pred, float* __restrict__ out_final,
    float* __restrict__ out_m14, float* __restrict__ out_m37)
{
    __shared__ float sdf[NTAB*8*16];
    __shared__ int   sgi[NTAB*14];
    __shared__ float sm14[NTAB*14];
    __shared__ float sm37[NTAB*37];
    __shared__ float slit[NTAB*14*3];
    __shared__ float predL[128][43];

    for (int i = threadIdx.x; i < NTAB*128; i += 128) sdf[i] = dframes[i];
    for (int i = threadIdx.x; i < NTAB*14; i += 128) { sgi[i] = gidx[i]; sm14[i] = a14m[i]; }
    for (int i = threadIdx.x; i < NTAB*37; i += 128) sm37[i] = a37m[i];
    for (int i = threadIdx.x; i < NTAB*42; i += 128) slit[i] = litp[i];
    __syncthreads();

    int p = blockIdx.x * 128 + threadIdx.x;
    int s = seq0i[p];

    const float* rg = rigids + (size_t)p * 7;
    float qw = rg[0], qx = rg[1], qy = rg[2], qz = rg[3];
    float tbx = rg[4], tby = rg[5], tbz = rg[6];
    float qn = 1.0f / sqrtf(qw*qw + qx*qx + qy*qy + qz*qz + 1e-8f);
    qw *= qn; qx *= qn; qy *= qn; qz *= qn;
    float rb[9];
    rb[0] = 1.f - 2.f*(qy*qy + qz*qz); rb[1] = 2.f*(qx*qy - qw*qz); rb[2] = 2.f*(qx*qz + qw*qy);
    rb[3] = 2.f*(qx*qy + qw*qz); rb[4] = 1.f - 2.f*(qx*qx + qz*qz); rb[5] = 2.f*(qy*qz - qw*qx);
    rb[6] = 2.f*(qx*qz - qw*qy); rb[7] = 2.f*(qy*qz + qw*qx); rb[8] = 1.f - 2.f*(qx*qx + qy*qy);

    float fr[8][9], ft[8][3];
    const float* ang = angles + (size_t)p * 14;
#pragma unroll
    for (int g = 0; g < 8; g++) {
        const float* df = &sdf[(s*8 + g)*16];
        float c, sn;
        if (g == 0) { c = 1.f; sn = 0.f; }
        else { sn = ang[(g-1)*2 + 0]; c = ang[(g-1)*2 + 1]; }
#pragma unroll
        for (int i = 0; i < 3; i++) {
            float d0 = df[i*4+0], d1 = df[i*4+1], d2 = df[i*4+2];
            fr[g][i*3+0] = d0;
            fr[g][i*3+1] = d1*c + d2*sn;
            fr[g][i*3+2] = d2*c - d1*sn;
            ft[g][i] = df[i*4+3];
        }
    }
#pragma unroll
    for (int g = 5; g <= 7; g++) {
        float r[9], t[3];
        const float* r1 = fr[g-1];
        const float* t1 = ft[g-1];
#pragma unroll
        for (int i = 0; i < 3; i++) {
#pragma unroll
            for (int j = 0; j < 3; j++)
                r[i*3+j] = r1[i*3+0]*fr[g][0*3+j] + r1[i*3+1]*fr[g][1*3+j] + r1[i*3+2]*fr[g][2*3+j];
            t[i] = r1[i*3+0]*ft[g][0] + r1[i*3+1]*ft[g][1] + r1[i*3+2]*ft[g][2] + t1[i];
        }
#pragma unroll
        for (int i = 0; i < 9; i++) fr[g][i] = r[i];
#pragma unroll
        for (int i = 0; i < 3; i++) ft[g][i] = t[i];
    }
#pragma unroll
    for (int g = 0; g < 8; g++) {
        float r[9], t[3];
#pragma unroll
        for (int i = 0; i < 3; i++) {
#pragma unroll
            for (int j = 0; j < 3; j++)
                r[i*3+j] = rb[i*3+0]*fr[g][0*3+j] + rb[i*3+1]*fr[g][1*3+j] + rb[i*3+2]*fr[g][2*3+j];
            t[i] = rb[i*3+0]*ft[g][0] + rb[i*3+1]*ft[g][1] + rb[i*3+2]*ft[g][2];
        }
#pragma unroll
        for (int i = 0; i < 9; i++) fr[g][i] = r[i];
        ft[g][0]=t[0]+tbx; ft[g][1]=t[1]+tby; ft[g][2]=t[2]+tbz;
    }
#pragma unroll
    for (int g = 0; g < 8; g++) {
#pragma unroll
        for (int a = 0; a < 14; a++) {
            if (sgi[s*14 + a] == g) {
                float m  = sm14[s*14 + a];
                float lx = slit[(s*14 + a)*3 + 0];
                float ly = slit[(s*14 + a)*3 + 1];
                float lz = slit[(s*14 + a)*3 + 2];
                float px = (fr[g][0]*lx + fr[g][1]*ly + fr[g][2]*lz + ft[g][0]) * m;
                float py = (fr[g][3]*lx + fr[g][4]*ly + fr[g][5]*lz + ft[g][1]) * m;
                float pz = (fr[g][6]*lx + fr[g][7]*ly + fr[g][8]*lz + ft[g][2]) * m;
                predL[threadIdx.x][a*3+0] = px;
                predL[threadIdx.x][a*3+1] = py;
                predL[threadIdx.x][a*3+2] = pz;
                out_pred[((size_t)p*14 + a)*3 + 0] = px;
                out_pred[((size_t)p*14 + a)*3 + 1] = py;
                out_pred[((size_t)p*14 + a)*3 + 2] = pz;
            }
        }
    }
#pragma unroll
    for (int a = 0; a < 14; a++) out_m14[(size_t)p*14 + a] = sm14[s*14 + a];

    const int* idx = residx + (size_t)p * 37;
#pragma unroll
    for (int a = 0; a < 37; a++) {
        int id = idx[a];
        out_final[((size_t)p*37 + a)*3 + 0] = predL[threadIdx.x][id*3+0];
        out_final[((size_t)p*37 + a)*3 + 1] = predL[threadIdx.x][id*3+1];
        out_final[((size_t)p*37 + a)*3 + 2] = predL[threadIdx.x][id*3+2];
        out_m37[(size_t)p*37 + a] = sm37[s*37 + a];
    }
}

extern "C" void kernel_launch(void* const* d_in, const int* in_sizes, int n_in,
                              void* d_out, int out_size, void* d_ws, size_t ws_size,
                              hipStream_t stream) {
    const float* act        = (const float*)d_in[0];
    const float* angles     = (const float*)d_in[1];
    const float* rigids     = (const float*)d_in[2];
    const int*   fixed_mask = (const int*)d_in[3];
    const int*   seq_t      = (const int*)d_in[4];
    const int*   residx     = (const int*)d_in[5];
    const float* lng        = (const float*)d_in[6];
    const float* lnb        = (const float*)d_in[7];
    const float* w1         = (const float*)d_in[8];
    const float* b1         = (const float*)d_in[9];
    const float* w2         = (const float*)d_in[10];
    const float* b2         = (const float*)d_in[11];
    const float* w3         = (const float*)d_in[12];
    const float* b3         = (const float*)d_in[13];
    const float* dfr        = (const float*)d_in[14];
    const int*   gidx       = (const int*)d_in[15];
    const float* a14m       = (const float*)d_in[16];
    const float* a37m       = (const float*)d_in[17];
    const float* litp       = (const float*)d_in[18];

    float* out        = (float*)d_out;
    float* out_logits = out;
    float* out_seq    = out_logits + (size_t)M_TOTAL * NRES;
    float* out_pred   = out_seq    + (size_t)M_TOTAL;
    float* out_final  = out_pred   + (size_t)M_TOTAL * 42;
    float* out_m14    = out_final  + (size_t)M_TOTAL * 111;
    float* out_m37    = out_m14    + (size_t)M_TOTAL * 14;

    char* wsp = (char*)d_ws;
    int*   seq0i = (int*)wsp;   wsp += (size_t)M_TOTAL * sizeof(int);
    float* mu    = (float*)wsp; wsp += (size_t)M_TOTAL * sizeof(float);
    float* rstd  = (float*)wsp; wsp += (size_t)M_TOTAL * sizeof(float);
    short* w1h   = (short*)wsp; wsp += (size_t)H_ * C_ * sizeof(short);
    short* w1l   = (short*)wsp; wsp += (size_t)H_ * C_ * sizeof(short);
    short* w2h   = (short*)wsp; wsp += (size_t)H_ * H_ * sizeof(short);
    short* w2l   = (short*)wsp; wsp += (size_t)H_ * H_ * sizeof(short);
    short* w3h   = (short*)wsp; wsp += (size_t)128 * H_ * sizeof(short);
    short* w3l   = (short*)wsp; wsp += (size_t)128 * H_ * sizeof(short);

    size_t fixed_bytes = (size_t)(wsp - (char*)d_ws);
    // chunkM: full M if workspace allows H1+H2 at full size, else 4096 (proven)
    size_t per_row = 2ull * H_ * sizeof(float);
    int chunkM = (ws_size - fixed_bytes >= (size_t)M_TOTAL * per_row) ? M_TOTAL : 4096;

    float* H1 = (float*)wsp; wsp += (size_t)chunkM * H_ * sizeof(float);
    float* H2 = (float*)wsp;

    conv_w_kernel<<<dim3(H_/32, C_/32), 256, 0, stream>>>(w1, w1h, w1l, C_, H_, H_);
    conv_w_kernel<<<dim3(H_/32, H_/32), 256, 0, stream>>>(w2, w2h, w2l, H_, H_, H_);
    conv_w_kernel<<<dim3(128/32, H_/32), 256, 0, stream>>>(w3, w3h, w3l, H_, NRES, 128);

    ln_stats_kernel<<<M_TOTAL/4, 256, 0, stream>>>(act, mu, rstd);

    for (int c = 0; c < M_TOTAL / chunkM; c++) {
        int m0 = c * chunkM;
        dim3 g1(H_/BN, chunkM/BM);
        mfma_gemm<<<g1, 256, 0, stream>>>(act + (size_t)m0 * C_, w1h, w1l, b1, H1,
                                          C_, H_, H_, mu + m0, rstd + m0, lng, lnb, 1);
        mfma_gemm<<<g1, 256, 0, stream>>>(H1, w2h, w2l, b2, H2,
                                          H_, H_, H_, nullptr, nullptr, nullptr, nullptr, 1);
        dim3 g3(1, chunkM/BM);
        mfma_gemm<<<g3, 256, 0, stream>>>(H2, w3h, w3l, b3, out_logits + (size_t)m0 * NRES,
                                          H_, NRES, NRES, nullptr, nullptr, nullptr, nullptr, 0);
    }

    argmax_kernel<<<M_TOTAL/256, 256, 0, stream>>>(out_logits, fixed_mask, seq_t,
                                                   out_seq, seq0i);

    geom_kernel<<<M_TOTAL/128, 128, 0, stream>>>(angles, rigids, seq0i, residx,
                                                 dfr, gidx, a14m, a37m, litp,
                                                 out_pred, out_final, out_m14, out_m37);
}

// Round 4
// 627.522 us; speedup vs baseline: 3.4049x; 2.2723x over previous
//
#include <hip/hip_runtime.h>
#include <math.h>

#define B_ 32
#define N_ 1024
#define C_ 384
#define H_ 1024
#define NRES 20
#define NTAB 21
#define M_TOTAL (B_*N_)   // 32768

#define BM 64
#define BN 128
#define BK 32
#define LDK 40   // LDS row stride (elements): keeps 16B alignment for b128 reads
#define KSPLIT 8

typedef __attribute__((ext_vector_type(8))) short bf16x8;
typedef __attribute__((ext_vector_type(4))) float f32x4;

__device__ inline short bf16_rne(float v) {
    unsigned u = __float_as_uint(v);
    unsigned r = u + 0x7fffu + ((u >> 16) & 1u);
    return (short)(r >> 16);
}
// v ~= hi + lo, each bf16 (RNE). ~16 mantissa bits captured.
__device__ inline void split2(float v, short& h, short& l) {
    unsigned u = __float_as_uint(v);
    unsigned r = (u + 0x7fffu + ((u >> 16) & 1u)) & 0xffff0000u;
    h = (short)(r >> 16);
    l = bf16_rne(v - __uint_as_float(r));
}

// ---------------- LN row stats: one wave per row ----------------
__global__ __launch_bounds__(256) void ln_stats_kernel(const float* __restrict__ act,
                                                       float* __restrict__ mu_out,
                                                       float* __restrict__ rstd_out) {
    int wave = threadIdx.x >> 6;
    int lane = threadIdx.x & 63;
    int row  = blockIdx.x * 4 + wave;
    const float* x = act + (size_t)row * C_;
    float v[6];
    float s = 0.f;
#pragma unroll
    for (int i = 0; i < 6; i++) { v[i] = x[lane + i*64]; s += v[i]; }
#pragma unroll
    for (int off = 32; off > 0; off >>= 1) s += __shfl_xor(s, off, 64);
    float mu = s * (1.0f/384.0f);
    float vs = 0.f;
#pragma unroll
    for (int i = 0; i < 6; i++) { float d = v[i]-mu; vs += d*d; }
#pragma unroll
    for (int off = 32; off > 0; off >>= 1) vs += __shfl_xor(vs, off, 64);
    float var = vs * (1.0f/384.0f);
    if (lane == 0) { mu_out[row] = mu; rstd_out[row] = 1.0f / sqrtf(var + 1e-5f); }
}

// ---------------- weight transpose + split-bf16 convert ----------------
__global__ __launch_bounds__(256) void conv_w_kernel(const float* __restrict__ w,
                                                     short* __restrict__ th,
                                                     short* __restrict__ tl,
                                                     int K, int N, int Npad) {
    __shared__ float t[32][33];
    int n0 = blockIdx.x * 32, k0 = blockIdx.y * 32;
    int tx = threadIdx.x & 31, ty = threadIdx.x >> 5;
#pragma unroll
    for (int i = ty; i < 32; i += 8) {
        int k = k0 + i, n = n0 + tx;
        t[i][tx] = (n < N) ? w[(size_t)k * N + n] : 0.f;
    }
    __syncthreads();
#pragma unroll
    for (int i = ty; i < 32; i += 8) {
        int n = n0 + i, k = k0 + tx;
        short h, l; split2(t[tx][i], h, l);
        th[(size_t)n * K + k] = h;
        tl[(size_t)n * K + k] = l;
    }
}

// ---------------- split-bf16 MFMA GEMM: 64x128 tile, split-bf16 output ----------------
// LN_A=true: A fp32, LN fused at stage. LN_A=false: A pre-split bf16 planes.
// Output: relu(acc + bias) split to Ch/Cl planes (ldc = N of this layer).
template<bool LN_A>
__global__ __launch_bounds__(256) void mlp_gemm(
    const float* __restrict__ A32,
    const short* __restrict__ Ahg, const short* __restrict__ Alg,
    const short* __restrict__ BTh, const short* __restrict__ BTl,
    const float* __restrict__ bias,
    short* __restrict__ Ch, short* __restrict__ Cl,
    int K, int ldc,
    const float* __restrict__ mu, const float* __restrict__ rstd,
    const float* __restrict__ lng, const float* __restrict__ lnb)
{
    __shared__ short Ah[BM][LDK], Al[BM][LDK];
    __shared__ short Bh[BN][LDK], Bl[BN][LDK];
    int tid = threadIdx.x;
    int m0 = blockIdx.y * BM;
    int n0 = blockIdx.x * BN;
    int lane = tid & 63, wv = tid >> 6;
    int wm = (wv & 1) * 32, wn = (wv >> 1) * 64;
    int fm = lane & 15, kg = lane >> 4;

    f32x4 acc[2][4] = {};

    // B-stage: 128 rows x 32 k, per thread 1 int4 per plane per p
    int br = tid >> 2;          // 0..63
    int bk8 = (tid & 3) * 8;

    for (int k0 = 0; k0 < K; k0 += BK) {
        if (LN_A) {
            // A tile 64x32 fp32: 2 float4/thread, LN + split
            int ar = tid >> 3;          // 0..31
            int ak = (tid & 7) * 4;
#pragma unroll
            for (int p = 0; p < 2; p++) {
                int row = m0 + ar + p * 32;
                float4 v = *(const float4*)&A32[(size_t)row * K + k0 + ak];
                float m_ = mu[row], rs = rstd[row];
                float4 g = *(const float4*)&lng[k0 + ak];
                float4 b = *(const float4*)&lnb[k0 + ak];
                v.x = (v.x - m_) * rs * g.x + b.x;
                v.y = (v.y - m_) * rs * g.y + b.y;
                v.z = (v.z - m_) * rs * g.z + b.z;
                v.w = (v.w - m_) * rs * g.w + b.w;
                short4 h4, l4;
                split2(v.x, h4.x, l4.x);
                split2(v.y, h4.y, l4.y);
                split2(v.z, h4.z, l4.z);
                split2(v.w, h4.w, l4.w);
                *(short4*)&Ah[ar + p*32][ak] = h4;
                *(short4*)&Al[ar + p*32][ak] = l4;
            }
        } else {
            // A tile 64x32 pre-split: 1 int4 per plane per thread
            int ar = tid >> 2;          // 0..63
            int ak8 = (tid & 3) * 8;
            int4 vh = *(const int4*)&Ahg[(size_t)(m0 + ar) * K + k0 + ak8];
            int4 vl = *(const int4*)&Alg[(size_t)(m0 + ar) * K + k0 + ak8];
            *(int4*)&Ah[ar][ak8] = vh;
            *(int4*)&Al[ar][ak8] = vl;
        }
#pragma unroll
        for (int p = 0; p < 2; p++) {
            int row = n0 + br + p * 64;
            int4 vh = *(const int4*)&BTh[(size_t)row * K + k0 + bk8];
            int4 vl = *(const int4*)&BTl[(size_t)row * K + k0 + bk8];
            *(int4*)&Bh[br + p*64][bk8] = vh;
            *(int4*)&Bl[br + p*64][bk8] = vl;
        }
        __syncthreads();

        bf16x8 a_h[2], a_l[2], b_h[4], b_l[4];
#pragma unroll
        for (int i = 0; i < 2; i++) {
            a_h[i] = *(bf16x8*)&Ah[wm + i*16 + fm][kg*8];
            a_l[i] = *(bf16x8*)&Al[wm + i*16 + fm][kg*8];
        }
#pragma unroll
        for (int j = 0; j < 4; j++) {
            b_h[j] = *(bf16x8*)&Bh[wn + j*16 + fm][kg*8];
            b_l[j] = *(bf16x8*)&Bl[wn + j*16 + fm][kg*8];
        }
#pragma unroll
        for (int i = 0; i < 2; i++)
#pragma unroll
            for (int j = 0; j < 4; j++) {
                f32x4 c = acc[i][j];
                c = __builtin_amdgcn_mfma_f32_16x16x32_bf16(a_l[i], b_h[j], c, 0, 0, 0);
                c = __builtin_amdgcn_mfma_f32_16x16x32_bf16(a_h[i], b_l[j], c, 0, 0, 0);
                c = __builtin_amdgcn_mfma_f32_16x16x32_bf16(a_h[i], b_h[j], c, 0, 0, 0);
                acc[i][j] = c;
            }
        __syncthreads();
    }

    // epilogue: bias + relu + split -> Ch/Cl
#pragma unroll
    for (int i = 0; i < 2; i++)
#pragma unroll
        for (int j = 0; j < 4; j++) {
            int col = n0 + wn + j*16 + fm;
            float bs = bias[col];
#pragma unroll
            for (int r = 0; r < 4; r++) {
                int row = m0 + wm + i*16 + kg*4 + r;
                float v = fmaxf(acc[i][j][r] + bs, 0.f);
                short h, l; split2(v, h, l);
                Ch[(size_t)row * ldc + col] = h;
                Cl[(size_t)row * ldc + col] = l;
            }
        }
}

// ---------------- GEMM3 split-K partial: 128 rows x 32 cols x 128 k-slice ----------------
__global__ __launch_bounds__(256) void gemm3_partial(
    const short* __restrict__ Ahg, const short* __restrict__ Alg,   // H2 planes, [M][1024]
    const short* __restrict__ BTh, const short* __restrict__ BTl,   // w3 planes, [128][1024]
    float* __restrict__ partial, int chunkM)
{
    __shared__ short Ah[128][LDK], Al[128][LDK];
    __shared__ short Bh[32][LDK], Bl[32][LDK];
    int tid = threadIdx.x;
    int kbase = blockIdx.x * 128;
    int m0 = blockIdx.y * 128;
    int lane = tid & 63, wv = tid >> 6;
    int wm = wv * 32;
    int fm = lane & 15, kg = lane >> 4;

    f32x4 acc[2][2] = {};

    int ar = tid >> 2;         // 0..63
    int ak8 = (tid & 3) * 8;
    int tid2 = tid & 127;
    int brr = tid2 >> 2;       // 0..31
    int bk8 = (tid2 & 3) * 8;

    for (int k0 = kbase; k0 < kbase + 128; k0 += BK) {
#pragma unroll
        for (int p = 0; p < 2; p++) {
            int row = m0 + ar + p * 64;
            int4 vh = *(const int4*)&Ahg[(size_t)row * H_ + k0 + ak8];
            int4 vl = *(const int4*)&Alg[(size_t)row * H_ + k0 + ak8];
            *(int4*)&Ah[ar + p*64][ak8] = vh;
            *(int4*)&Al[ar + p*64][ak8] = vl;
        }
        if (tid < 128) {
            int4 vh = *(const int4*)&BTh[(size_t)brr * H_ + k0 + bk8];
            *(int4*)&Bh[brr][bk8] = vh;
        } else {
            int4 vl = *(const int4*)&BTl[(size_t)brr * H_ + k0 + bk8];
            *(int4*)&Bl[brr][bk8] = vl;
        }
        __syncthreads();

        bf16x8 a_h[2], a_l[2], b_h[2], b_l[2];
#pragma unroll
        for (int i = 0; i < 2; i++) {
            a_h[i] = *(bf16x8*)&Ah[wm + i*16 + fm][kg*8];
            a_l[i] = *(bf16x8*)&Al[wm + i*16 + fm][kg*8];
        }
#pragma unroll
        for (int j = 0; j < 2; j++) {
            b_h[j] = *(bf16x8*)&Bh[j*16 + fm][kg*8];
            b_l[j] = *(bf16x8*)&Bl[j*16 + fm][kg*8];
        }
#pragma unroll
        for (int i = 0; i < 2; i++)
#pragma unroll
            for (int j = 0; j < 2; j++) {
                f32x4 c = acc[i][j];
                c = __builtin_amdgcn_mfma_f32_16x16x32_bf16(a_l[i], b_h[j], c, 0, 0, 0);
                c = __builtin_amdgcn_mfma_f32_16x16x32_bf16(a_h[i], b_l[j], c, 0, 0, 0);
                c = __builtin_amdgcn_mfma_f32_16x16x32_bf16(a_h[i], b_h[j], c, 0, 0, 0);
                acc[i][j] = c;
            }
        __syncthreads();
    }

    float* pp = partial + (size_t)blockIdx.x * chunkM * 32;
#pragma unroll
    for (int i = 0; i < 2; i++)
#pragma unroll
        for (int j = 0; j < 2; j++) {
            int col = j*16 + fm;
#pragma unroll
            for (int r = 0; r < 4; r++) {
                int row = m0 + wm + i*16 + kg*4 + r;
                pp[(size_t)row * 32 + col] = acc[i][j][r];
            }
        }
}

// ---------------- logits reduce + bias + argmax + fixed-mask merge ----------------
__global__ __launch_bounds__(256) void logits_argmax(
    const float* __restrict__ partial, int chunkM, int m0,
    const float* __restrict__ b3,
    const int* __restrict__ fixed_mask, const int* __restrict__ seq_t,
    float* __restrict__ out_logits, float* __restrict__ seq_out,
    int* __restrict__ seq_int)
{
    int rl = blockIdx.x * blockDim.x + threadIdx.x;    // chunk-local row
    int row = m0 + rl;
    float best = -1e30f; int bi = 0;
    float* lg = out_logits + (size_t)row * NRES;
#pragma unroll 4
    for (int n = 0; n < NRES; n++) {
        float s = b3[n];
#pragma unroll
        for (int p = 0; p < KSPLIT; p++)
            s += partial[((size_t)p * chunkM + rl) * 32 + n];
        lg[n] = s;
        if (s > best) { best = s; bi = n; }
    }
    int fm = fixed_mask[row];
    int s = fm ? seq_t[row] : bi;
    seq_int[row] = s;
    seq_out[row] = (float)s;
}

// ---------------- geometry: one thread per (b,n) ----------------
__global__ __launch_bounds__(128) void geom_kernel(
    const float* __restrict__ angles, const float* __restrict__ rigids,
    const int* __restrict__ seq0i, const int* __restrict__ residx,
    const float* __restrict__ dframes, const int* __restrict__ gidx,
    const float* __restrict__ a14m, const float* __restrict__ a37m,
    const float* __restrict__ litp,
    float* __restrict__ out_pred, float* __restrict__ out_final,
    float* __restrict__ out_m14, float* __restrict__ out_m37)
{
    __shared__ float sdf[NTAB*8*16];
    __shared__ int   sgi[NTAB*14];
    __shared__ float sm14[NTAB*14];
    __shared__ float sm37[NTAB*37];
    __shared__ float slit[NTAB*14*3];
    __shared__ float predL[128][43];

    for (int i = threadIdx.x; i < NTAB*128; i += 128) sdf[i] = dframes[i];
    for (int i = threadIdx.x; i < NTAB*14; i += 128) { sgi[i] = gidx[i]; sm14[i] = a14m[i]; }
    for (int i = threadIdx.x; i < NTAB*37; i += 128) sm37[i] = a37m[i];
    for (int i = threadIdx.x; i < NTAB*42; i += 128) slit[i] = litp[i];
    __syncthreads();

    int p = blockIdx.x * 128 + threadIdx.x;
    int s = seq0i[p];

    const float* rg = rigids + (size_t)p * 7;
    float qw = rg[0], qx = rg[1], qy = rg[2], qz = rg[3];
    float tbx = rg[4], tby = rg[5], tbz = rg[6];
    float qn = 1.0f / sqrtf(qw*qw + qx*qx + qy*qy + qz*qz + 1e-8f);
    qw *= qn; qx *= qn; qy *= qn; qz *= qn;
    float rb[9];
    rb[0] = 1.f - 2.f*(qy*qy + qz*qz); rb[1] = 2.f*(qx*qy - qw*qz); rb[2] = 2.f*(qx*qz + qw*qy);
    rb[3] = 2.f*(qx*qy + qw*qz); rb[4] = 1.f - 2.f*(qx*qx + qz*qz); rb[5] = 2.f*(qy*qz - qw*qx);
    rb[6] = 2.f*(qx*qz - qw*qy); rb[7] = 2.f*(qy*qz + qw*qx); rb[8] = 1.f - 2.f*(qx*qx + qy*qy);

    float fr[8][9], ft[8][3];
    const float* ang = angles + (size_t)p * 14;
#pragma unroll
    for (int g = 0; g < 8; g++) {
        const float* df = &sdf[(s*8 + g)*16];
        float c, sn;
        if (g == 0) { c = 1.f; sn = 0.f; }
        else { sn = ang[(g-1)*2 + 0]; c = ang[(g-1)*2 + 1]; }
#pragma unroll
        for (int i = 0; i < 3; i++) {
            float d0 = df[i*4+0], d1 = df[i*4+1], d2 = df[i*4+2];
            fr[g][i*3+0] = d0;
            fr[g][i*3+1] = d1*c + d2*sn;
            fr[g][i*3+2] = d2*c - d1*sn;
            ft[g][i] = df[i*4+3];
        }
    }
#pragma unroll
    for (int g = 5; g <= 7; g++) {
        float r[9], t[3];
        const float* r1 = fr[g-1];
        const float* t1 = ft[g-1];
#pragma unroll
        for (int i = 0; i < 3; i++) {
#pragma unroll
            for (int j = 0; j < 3; j++)
                r[i*3+j] = r1[i*3+0]*fr[g][0*3+j] + r1[i*3+1]*fr[g][1*3+j] + r1[i*3+2]*fr[g][2*3+j];
            t[i] = r1[i*3+0]*ft[g][0] + r1[i*3+1]*ft[g][1] + r1[i*3+2]*ft[g][2] + t1[i];
        }
#pragma unroll
        for (int i = 0; i < 9; i++) fr[g][i] = r[i];
#pragma unroll
        for (int i = 0; i < 3; i++) ft[g][i] = t[i];
    }
#pragma unroll
    for (int g = 0; g < 8; g++) {
        float r[9], t[3];
#pragma unroll
        for (int i = 0; i < 3; i++) {
#pragma unroll
            for (int j = 0; j < 3; j++)
                r[i*3+j] = rb[i*3+0]*fr[g][0*3+j] + rb[i*3+1]*fr[g][1*3+j] + rb[i*3+2]*fr[g][2*3+j];
            t[i] = rb[i*3+0]*ft[g][0] + rb[i*3+1]*ft[g][1] + rb[i*3+2]*ft[g][2];
        }
#pragma unroll
        for (int i = 0; i < 9; i++) fr[g][i] = r[i];
        ft[g][0]=t[0]+tbx; ft[g][1]=t[1]+tby; ft[g][2]=t[2]+tbz;
    }
#pragma unroll
    for (int g = 0; g < 8; g++) {
#pragma unroll
        for (int a = 0; a < 14; a++) {
            if (sgi[s*14 + a] == g) {
                float m  = sm14[s*14 + a];
                float lx = slit[(s*14 + a)*3 + 0];
                float ly = slit[(s*14 + a)*3 + 1];
                float lz = slit[(s*14 + a)*3 + 2];
                float px = (fr[g][0]*lx + fr[g][1]*ly + fr[g][2]*lz + ft[g][0]) * m;
                float py = (fr[g][3]*lx + fr[g][4]*ly + fr[g][5]*lz + ft[g][1]) * m;
                float pz = (fr[g][6]*lx + fr[g][7]*ly + fr[g][8]*lz + ft[g][2]) * m;
                predL[threadIdx.x][a*3+0] = px;
                predL[threadIdx.x][a*3+1] = py;
                predL[threadIdx.x][a*3+2] = pz;
                out_pred[((size_t)p*14 + a)*3 + 0] = px;
                out_pred[((size_t)p*14 + a)*3 + 1] = py;
                out_pred[((size_t)p*14 + a)*3 + 2] = pz;
            }
        }
    }
#pragma unroll
    for (int a = 0; a < 14; a++) out_m14[(size_t)p*14 + a] = sm14[s*14 + a];

    const int* idx = residx + (size_t)p * 37;
#pragma unroll
    for (int a = 0; a < 37; a++) {
        int id = idx[a];
        out_final[((size_t)p*37 + a)*3 + 0] = predL[threadIdx.x][id*3+0];
        out_final[((size_t)p*37 + a)*3 + 1] = predL[threadIdx.x][id*3+1];
        out_final[((size_t)p*37 + a)*3 + 2] = predL[threadIdx.x][id*3+2];
        out_m37[(size_t)p*37 + a] = sm37[s*37 + a];
    }
}

extern "C" void kernel_launch(void* const* d_in, const int* in_sizes, int n_in,
                              void* d_out, int out_size, void* d_ws, size_t ws_size,
                              hipStream_t stream) {
    const float* act        = (const float*)d_in[0];
    const float* angles     = (const float*)d_in[1];
    const float* rigids     = (const float*)d_in[2];
    const int*   fixed_mask = (const int*)d_in[3];
    const int*   seq_t      = (const int*)d_in[4];
    const int*   residx     = (const int*)d_in[5];
    const float* lng        = (const float*)d_in[6];
    const float* lnb        = (const float*)d_in[7];
    const float* w1         = (const float*)d_in[8];
    const float* b1         = (const float*)d_in[9];
    const float* w2         = (const float*)d_in[10];
    const float* b2         = (const float*)d_in[11];
    const float* w3         = (const float*)d_in[12];
    const float* b3         = (const float*)d_in[13];
    const float* dfr        = (const float*)d_in[14];
    const int*   gidx       = (const int*)d_in[15];
    const float* a14m       = (const float*)d_in[16];
    const float* a37m       = (const float*)d_in[17];
    const float* litp       = (const float*)d_in[18];

    float* out        = (float*)d_out;
    float* out_logits = out;
    float* out_seq    = out_logits + (size_t)M_TOTAL * NRES;
    float* out_pred   = out_seq    + (size_t)M_TOTAL;
    float* out_final  = out_pred   + (size_t)M_TOTAL * 42;
    float* out_m14    = out_final  + (size_t)M_TOTAL * 111;
    float* out_m37    = out_m14    + (size_t)M_TOTAL * 14;

    char* wsp = (char*)d_ws;
    int*   seq0i = (int*)wsp;   wsp += (size_t)M_TOTAL * sizeof(int);
    float* mu    = (float*)wsp; wsp += (size_t)M_TOTAL * sizeof(float);
    float* rstd  = (float*)wsp; wsp += (size_t)M_TOTAL * sizeof(float);
    short* w1h   = (short*)wsp; wsp += (size_t)H_ * C_ * sizeof(short);
    short* w1l   = (short*)wsp; wsp += (size_t)H_ * C_ * sizeof(short);
    short* w2h   = (short*)wsp; wsp += (size_t)H_ * H_ * sizeof(short);
    short* w2l   = (short*)wsp; wsp += (size_t)H_ * H_ * sizeof(short);
    short* w3h   = (short*)wsp; wsp += (size_t)128 * H_ * sizeof(short);
    short* w3l   = (short*)wsp; wsp += (size_t)128 * H_ * sizeof(short);

    size_t fixed_bytes = (size_t)(wsp - (char*)d_ws);
    // per-chunk: H1h/H1l (2B each) + H2h/H2l (2B each) per hidden elem + partials
    size_t per_row = 4ull * H_ * sizeof(short) + (size_t)KSPLIT * 32 * sizeof(float);
    int chunkM = 4096;
    if (ws_size - fixed_bytes >= (size_t)M_TOTAL * per_row)      chunkM = M_TOTAL;
    else if (ws_size - fixed_bytes >= (size_t)16384 * per_row)   chunkM = 16384;
    else if (ws_size - fixed_bytes >= (size_t)8192 * per_row)    chunkM = 8192;

    short* H1h = (short*)wsp; wsp += (size_t)chunkM * H_ * sizeof(short);
    short* H1l = (short*)wsp; wsp += (size_t)chunkM * H_ * sizeof(short);
    short* H2h = (short*)wsp; wsp += (size_t)chunkM * H_ * sizeof(short);
    short* H2l = (short*)wsp; wsp += (size_t)chunkM * H_ * sizeof(short);
    float* part = (float*)wsp;

    conv_w_kernel<<<dim3(H_/32, C_/32), 256, 0, stream>>>(w1, w1h, w1l, C_, H_, H_);
    conv_w_kernel<<<dim3(H_/32, H_/32), 256, 0, stream>>>(w2, w2h, w2l, H_, H_, H_);
    conv_w_kernel<<<dim3(128/32, H_/32), 256, 0, stream>>>(w3, w3h, w3l, H_, NRES, 128);

    ln_stats_kernel<<<M_TOTAL/4, 256, 0, stream>>>(act, mu, rstd);

    for (int c = 0; c < M_TOTAL / chunkM; c++) {
        int m0 = c * chunkM;
        dim3 g1(H_/BN, chunkM/BM);
        mlp_gemm<true><<<g1, 256, 0, stream>>>(act + (size_t)m0 * C_, nullptr, nullptr,
                                               w1h, w1l, b1, H1h, H1l, C_, H_,
                                               mu + m0, rstd + m0, lng, lnb);
        mlp_gemm<false><<<g1, 256, 0, stream>>>(nullptr, H1h, H1l,
                                                w2h, w2l, b2, H2h, H2l, H_, H_,
                                                nullptr, nullptr, nullptr, nullptr);
        gemm3_partial<<<dim3(KSPLIT, chunkM/128), 256, 0, stream>>>(H2h, H2l, w3h, w3l,
                                                                    part, chunkM);
        logits_argmax<<<chunkM/256, 256, 0, stream>>>(part, chunkM, m0, b3,
                                                      fixed_mask, seq_t,
                                                      out_logits, out_seq, seq0i);
    }

    geom_kernel<<<M_TOTAL/128, 128, 0, stream>>>(angles, rigids, seq0i, residx,
                                                 dfr, gidx, a14m, a37m, litp,
                                                 out_pred, out_final, out_m14, out_m37);
}

// Round 5
// 582.750 us; speedup vs baseline: 3.6665x; 1.0768x over previous
//
#include <hip/hip_runtime.h>
#include <math.h>

#define B_ 32
#define N_ 1024
#define C_ 384
#define H_ 1024
#define NRES 20
#define NTAB 21
#define M_TOTAL (B_*N_)   // 32768

#define BM 64
#define BN 128
#define BK 32
#define LDK 40   // LDS row stride (elements): keeps 16B alignment for b128 reads
#define KSPLIT 8

typedef __attribute__((ext_vector_type(8))) short bf16x8;
typedef __attribute__((ext_vector_type(4))) float f32x4;

__device__ inline short bf16_rne(float v) {
    unsigned u = __float_as_uint(v);
    unsigned r = u + 0x7fffu + ((u >> 16) & 1u);
    return (short)(r >> 16);
}
// v ~= hi + lo, each bf16 (RNE). ~16 mantissa bits captured.
__device__ inline void split2(float v, short& h, short& l) {
    unsigned u = __float_as_uint(v);
    unsigned r = (u + 0x7fffu + ((u >> 16) & 1u)) & 0xffff0000u;
    h = (short)(r >> 16);
    l = bf16_rne(v - __uint_as_float(r));
}

// ---------------- LN row stats: one wave per row ----------------
__global__ __launch_bounds__(256) void ln_stats_kernel(const float* __restrict__ act,
                                                       float* __restrict__ mu_out,
                                                       float* __restrict__ rstd_out) {
    int wave = threadIdx.x >> 6;
    int lane = threadIdx.x & 63;
    int row  = blockIdx.x * 4 + wave;
    const float* x = act + (size_t)row * C_;
    float v[6];
    float s = 0.f;
#pragma unroll
    for (int i = 0; i < 6; i++) { v[i] = x[lane + i*64]; s += v[i]; }
#pragma unroll
    for (int off = 32; off > 0; off >>= 1) s += __shfl_xor(s, off, 64);
    float mu = s * (1.0f/384.0f);
    float vs = 0.f;
#pragma unroll
    for (int i = 0; i < 6; i++) { float d = v[i]-mu; vs += d*d; }
#pragma unroll
    for (int off = 32; off > 0; off >>= 1) vs += __shfl_xor(vs, off, 64);
    float var = vs * (1.0f/384.0f);
    if (lane == 0) { mu_out[row] = mu; rstd_out[row] = 1.0f / sqrtf(var + 1e-5f); }
}

// ---------------- weight transpose + split-bf16 convert ----------------
__global__ __launch_bounds__(256) void conv_w_kernel(const float* __restrict__ w,
                                                     short* __restrict__ th,
                                                     short* __restrict__ tl,
                                                     int K, int N, int Npad) {
    __shared__ float t[32][33];
    int n0 = blockIdx.x * 32, k0 = blockIdx.y * 32;
    int tx = threadIdx.x & 31, ty = threadIdx.x >> 5;
#pragma unroll
    for (int i = ty; i < 32; i += 8) {
        int k = k0 + i, n = n0 + tx;
        t[i][tx] = (n < N) ? w[(size_t)k * N + n] : 0.f;
    }
    __syncthreads();
#pragma unroll
    for (int i = ty; i < 32; i += 8) {
        int n = n0 + i, k = k0 + tx;
        short h, l; split2(t[tx][i], h, l);
        th[(size_t)n * K + k] = h;
        tl[(size_t)n * K + k] = l;
    }
}

// ---------------- GEMM1: LN-fused split-bf16 MFMA, 64x128 tile ----------------
// grid: (chunkM/BM, H/BN) -- x = row tiles (same-A blocks land on same XCD)
__global__ __launch_bounds__(256) void mlp_gemm1(
    const float* __restrict__ A32,
    const short* __restrict__ BTh, const short* __restrict__ BTl,
    const float* __restrict__ bias,
    short* __restrict__ Ch, short* __restrict__ Cl,
    int K, int ldc,
    const float* __restrict__ mu, const float* __restrict__ rstd,
    const float* __restrict__ lng, const float* __restrict__ lnb)
{
    __shared__ short Ah[BM][LDK], Al[BM][LDK];
    __shared__ short Bh[BN][LDK], Bl[BN][LDK];
    int tid = threadIdx.x;
    int m0 = blockIdx.x * BM;
    int n0 = blockIdx.y * BN;
    int lane = tid & 63, wv = tid >> 6;
    int wm = (wv & 1) * 32, wn = (wv >> 1) * 64;
    int fm = lane & 15, kg = lane >> 4;

    f32x4 acc[2][4] = {};

    int br = tid >> 2;          // 0..63
    int bk8 = (tid & 3) * 8;
    int ar = tid >> 3;          // 0..31
    int ak = (tid & 7) * 4;
    // preload LN row stats for my 2 staging rows
    float mur[2], rsr[2];
#pragma unroll
    for (int p = 0; p < 2; p++) { mur[p] = mu[m0 + ar + p*32]; rsr[p] = rstd[m0 + ar + p*32]; }

    for (int k0 = 0; k0 < K; k0 += BK) {
#pragma unroll
        for (int p = 0; p < 2; p++) {
            int row = m0 + ar + p * 32;
            float4 v = *(const float4*)&A32[(size_t)row * K + k0 + ak];
            float4 g = *(const float4*)&lng[k0 + ak];
            float4 b = *(const float4*)&lnb[k0 + ak];
            v.x = (v.x - mur[p]) * rsr[p] * g.x + b.x;
            v.y = (v.y - mur[p]) * rsr[p] * g.y + b.y;
            v.z = (v.z - mur[p]) * rsr[p] * g.z + b.z;
            v.w = (v.w - mur[p]) * rsr[p] * g.w + b.w;
            short4 h4, l4;
            split2(v.x, h4.x, l4.x);
            split2(v.y, h4.y, l4.y);
            split2(v.z, h4.z, l4.z);
            split2(v.w, h4.w, l4.w);
            *(short4*)&Ah[ar + p*32][ak] = h4;
            *(short4*)&Al[ar + p*32][ak] = l4;
        }
#pragma unroll
        for (int p = 0; p < 2; p++) {
            int row = n0 + br + p * 64;
            int4 vh = *(const int4*)&BTh[(size_t)row * K + k0 + bk8];
            int4 vl = *(const int4*)&BTl[(size_t)row * K + k0 + bk8];
            *(int4*)&Bh[br + p*64][bk8] = vh;
            *(int4*)&Bl[br + p*64][bk8] = vl;
        }
        __syncthreads();

        bf16x8 a_h[2], a_l[2], b_h[4], b_l[4];
#pragma unroll
        for (int i = 0; i < 2; i++) {
            a_h[i] = *(bf16x8*)&Ah[wm + i*16 + fm][kg*8];
            a_l[i] = *(bf16x8*)&Al[wm + i*16 + fm][kg*8];
        }
#pragma unroll
        for (int j = 0; j < 4; j++) {
            b_h[j] = *(bf16x8*)&Bh[wn + j*16 + fm][kg*8];
            b_l[j] = *(bf16x8*)&Bl[wn + j*16 + fm][kg*8];
        }
#pragma unroll
        for (int i = 0; i < 2; i++)
#pragma unroll
            for (int j = 0; j < 4; j++) {
                f32x4 c = acc[i][j];
                c = __builtin_amdgcn_mfma_f32_16x16x32_bf16(a_l[i], b_h[j], c, 0, 0, 0);
                c = __builtin_amdgcn_mfma_f32_16x16x32_bf16(a_h[i], b_l[j], c, 0, 0, 0);
                c = __builtin_amdgcn_mfma_f32_16x16x32_bf16(a_h[i], b_h[j], c, 0, 0, 0);
                acc[i][j] = c;
            }
        __syncthreads();
    }

#pragma unroll
    for (int i = 0; i < 2; i++)
#pragma unroll
        for (int j = 0; j < 4; j++) {
            int col = n0 + wn + j*16 + fm;
            float bs = bias[col];
#pragma unroll
            for (int r = 0; r < 4; r++) {
                int row = m0 + wm + i*16 + kg*4 + r;
                float v = fmaxf(acc[i][j][r] + bs, 0.f);
                short h, l; split2(v, h, l);
                Ch[(size_t)row * ldc + col] = h;
                Cl[(size_t)row * ldc + col] = l;
            }
        }
}

// ---------------- GEMM2: pre-split A, 128x128 tile, 64x64 per wave (m97 structure) ----
// grid: (chunkM/128, H/128) -- x = row tiles
__global__ __launch_bounds__(256) void mlp_gemm2_128(
    const short* __restrict__ Ahg, const short* __restrict__ Alg,
    const short* __restrict__ BTh, const short* __restrict__ BTl,
    const float* __restrict__ bias,
    short* __restrict__ Ch, short* __restrict__ Cl,
    int K, int ldc)
{
    __shared__ short Ah[128][LDK], Al[128][LDK];
    __shared__ short Bh[128][LDK], Bl[128][LDK];
    int tid = threadIdx.x;
    int m0 = blockIdx.x * 128;
    int n0 = blockIdx.y * 128;
    int lane = tid & 63, wv = tid >> 6;
    int wm = (wv & 1) * 64, wn = (wv >> 1) * 64;
    int fm = lane & 15, kg = lane >> 4;

    f32x4 acc[4][4] = {};

    int ar = tid >> 2;          // 0..63
    int ak8 = (tid & 3) * 8;

    for (int k0 = 0; k0 < K; k0 += BK) {
#pragma unroll
        for (int p = 0; p < 2; p++) {
            int row = ar + p * 64;
            int4 vh = *(const int4*)&Ahg[(size_t)(m0 + row) * K + k0 + ak8];
            int4 vl = *(const int4*)&Alg[(size_t)(m0 + row) * K + k0 + ak8];
            *(int4*)&Ah[row][ak8] = vh;
            *(int4*)&Al[row][ak8] = vl;
            int4 wh = *(const int4*)&BTh[(size_t)(n0 + row) * K + k0 + ak8];
            int4 wl = *(const int4*)&BTl[(size_t)(n0 + row) * K + k0 + ak8];
            *(int4*)&Bh[row][ak8] = wh;
            *(int4*)&Bl[row][ak8] = wl;
        }
        __syncthreads();

        bf16x8 a_h[4], a_l[4], b_h[4], b_l[4];
#pragma unroll
        for (int i = 0; i < 4; i++) {
            a_h[i] = *(bf16x8*)&Ah[wm + i*16 + fm][kg*8];
            a_l[i] = *(bf16x8*)&Al[wm + i*16 + fm][kg*8];
            b_h[i] = *(bf16x8*)&Bh[wn + i*16 + fm][kg*8];
            b_l[i] = *(bf16x8*)&Bl[wn + i*16 + fm][kg*8];
        }
#pragma unroll
        for (int i = 0; i < 4; i++)
#pragma unroll
            for (int j = 0; j < 4; j++) {
                f32x4 c = acc[i][j];
                c = __builtin_amdgcn_mfma_f32_16x16x32_bf16(a_l[i], b_h[j], c, 0, 0, 0);
                c = __builtin_amdgcn_mfma_f32_16x16x32_bf16(a_h[i], b_l[j], c, 0, 0, 0);
                c = __builtin_amdgcn_mfma_f32_16x16x32_bf16(a_h[i], b_h[j], c, 0, 0, 0);
                acc[i][j] = c;
            }
        __syncthreads();
    }

#pragma unroll
    for (int i = 0; i < 4; i++)
#pragma unroll
        for (int j = 0; j < 4; j++) {
            int col = n0 + wn + j*16 + fm;
            float bs = bias[col];
#pragma unroll
            for (int r = 0; r < 4; r++) {
                int row = m0 + wm + i*16 + kg*4 + r;
                float v = fmaxf(acc[i][j][r] + bs, 0.f);
                short h, l; split2(v, h, l);
                Ch[(size_t)row * ldc + col] = h;
                Cl[(size_t)row * ldc + col] = l;
            }
        }
}

// ---------------- GEMM3 split-K partial: 128 rows x 32 cols x 128 k-slice ----------------
__global__ __launch_bounds__(256) void gemm3_partial(
    const short* __restrict__ Ahg, const short* __restrict__ Alg,   // H2 planes, [M][1024]
    const short* __restrict__ BTh, const short* __restrict__ BTl,   // w3 planes, [128][1024]
    float* __restrict__ partial, int chunkM)
{
    __shared__ short Ah[128][LDK], Al[128][LDK];
    __shared__ short Bh[32][LDK], Bl[32][LDK];
    int tid = threadIdx.x;
    int kbase = blockIdx.x * 128;
    int m0 = blockIdx.y * 128;
    int lane = tid & 63, wv = tid >> 6;
    int wm = wv * 32;
    int fm = lane & 15, kg = lane >> 4;

    f32x4 acc[2][2] = {};

    int ar = tid >> 2;         // 0..63
    int ak8 = (tid & 3) * 8;
    int tid2 = tid & 127;
    int brr = tid2 >> 2;       // 0..31
    int bk8 = (tid2 & 3) * 8;

    for (int k0 = kbase; k0 < kbase + 128; k0 += BK) {
#pragma unroll
        for (int p = 0; p < 2; p++) {
            int row = m0 + ar + p * 64;
            int4 vh = *(const int4*)&Ahg[(size_t)row * H_ + k0 + ak8];
            int4 vl = *(const int4*)&Alg[(size_t)row * H_ + k0 + ak8];
            *(int4*)&Ah[ar + p*64][ak8] = vh;
            *(int4*)&Al[ar + p*64][ak8] = vl;
        }
        if (tid < 128) {
            int4 vh = *(const int4*)&BTh[(size_t)brr * H_ + k0 + bk8];
            *(int4*)&Bh[brr][bk8] = vh;
        } else {
            int4 vl = *(const int4*)&BTl[(size_t)brr * H_ + k0 + bk8];
            *(int4*)&Bl[brr][bk8] = vl;
        }
        __syncthreads();

        bf16x8 a_h[2], a_l[2], b_h[2], b_l[2];
#pragma unroll
        for (int i = 0; i < 2; i++) {
            a_h[i] = *(bf16x8*)&Ah[wm + i*16 + fm][kg*8];
            a_l[i] = *(bf16x8*)&Al[wm + i*16 + fm][kg*8];
        }
#pragma unroll
        for (int j = 0; j < 2; j++) {
            b_h[j] = *(bf16x8*)&Bh[j*16 + fm][kg*8];
            b_l[j] = *(bf16x8*)&Bl[j*16 + fm][kg*8];
        }
#pragma unroll
        for (int i = 0; i < 2; i++)
#pragma unroll
            for (int j = 0; j < 2; j++) {
                f32x4 c = acc[i][j];
                c = __builtin_amdgcn_mfma_f32_16x16x32_bf16(a_l[i], b_h[j], c, 0, 0, 0);
                c = __builtin_amdgcn_mfma_f32_16x16x32_bf16(a_h[i], b_l[j], c, 0, 0, 0);
                c = __builtin_amdgcn_mfma_f32_16x16x32_bf16(a_h[i], b_h[j], c, 0, 0, 0);
                acc[i][j] = c;
            }
        __syncthreads();
    }

    float* pp = partial + (size_t)blockIdx.x * chunkM * 32;
#pragma unroll
    for (int i = 0; i < 2; i++)
#pragma unroll
        for (int j = 0; j < 2; j++) {
            int col = j*16 + fm;
#pragma unroll
            for (int r = 0; r < 4; r++) {
                int row = m0 + wm + i*16 + kg*4 + r;
                pp[(size_t)row * 32 + col] = acc[i][j][r];
            }
        }
}

// ---------------- logits reduce + bias + argmax + fixed-mask merge ----------------
__global__ __launch_bounds__(256) void logits_argmax(
    const float* __restrict__ partial, int chunkM, int m0,
    const float* __restrict__ b3,
    const int* __restrict__ fixed_mask, const int* __restrict__ seq_t,
    float* __restrict__ out_logits, float* __restrict__ seq_out,
    int* __restrict__ seq_int)
{
    int rl = blockIdx.x * blockDim.x + threadIdx.x;    // chunk-local row
    int row = m0 + rl;
    float best = -1e30f; int bi = 0;
    float* lg = out_logits + (size_t)row * NRES;
#pragma unroll 4
    for (int n = 0; n < NRES; n++) {
        float s = b3[n];
#pragma unroll
        for (int p = 0; p < KSPLIT; p++)
            s += partial[((size_t)p * chunkM + rl) * 32 + n];
        lg[n] = s;
        if (s > best) { best = s; bi = n; }
    }
    int fm = fixed_mask[row];
    int s = fm ? seq_t[row] : bi;
    seq_int[row] = s;
    seq_out[row] = (float)s;
}

// ---------------- geometry: one thread per (b,n) ----------------
__global__ __launch_bounds__(128) void geom_kernel(
    const float* __restrict__ angles, const float* __restrict__ rigids,
    const int* __restrict__ seq0i, const int* __restrict__ residx,
    const float* __restrict__ dframes, const int* __restrict__ gidx,
    const float* __restrict__ a14m, const float* __restrict__ a37m,
    const float* __restrict__ litp,
    float* __restrict__ out_pred, float* __restrict__ out_final,
    float* __restrict__ out_m14, float* __restrict__ out_m37)
{
    __shared__ float sdf[NTAB*8*16];
    __shared__ int   sgi[NTAB*14];
    __shared__ float sm14[NTAB*14];
    __shared__ float sm37[NTAB*37];
    __shared__ float slit[NTAB*14*3];
    __shared__ float predL[128][43];

    for (int i = threadIdx.x; i < NTAB*128; i += 128) sdf[i] = dframes[i];
    for (int i = threadIdx.x; i < NTAB*14; i += 128) { sgi[i] = gidx[i]; sm14[i] = a14m[i]; }
    for (int i = threadIdx.x; i < NTAB*37; i += 128) sm37[i] = a37m[i];
    for (int i = threadIdx.x; i < NTAB*42; i += 128) slit[i] = litp[i];
    __syncthreads();

    int p = blockIdx.x * 128 + threadIdx.x;
    int s = seq0i[p];

    const float* rg = rigids + (size_t)p * 7;
    float qw = rg[0], qx = rg[1], qy = rg[2], qz = rg[3];
    float tbx = rg[4], tby = rg[5], tbz = rg[6];
    float qn = 1.0f / sqrtf(qw*qw + qx*qx + qy*qy + qz*qz + 1e-8f);
    qw *= qn; qx *= qn; qy *= qn; qz *= qn;
    float rb[9];
    rb[0] = 1.f - 2.f*(qy*qy + qz*qz); rb[1] = 2.f*(qx*qy - qw*qz); rb[2] = 2.f*(qx*qz + qw*qy);
    rb[3] = 2.f*(qx*qy + qw*qz); rb[4] = 1.f - 2.f*(qx*qx + qz*qz); rb[5] = 2.f*(qy*qz - qw*qx);
    rb[6] = 2.f*(qx*qz - qw*qy); rb[7] = 2.f*(qy*qz + qw*qx); rb[8] = 1.f - 2.f*(qx*qx + qy*qy);

    float fr[8][9], ft[8][3];
    const float* ang = angles + (size_t)p * 14;
#pragma unroll
    for (int g = 0; g < 8; g++) {
        const float* df = &sdf[(s*8 + g)*16];
        float c, sn;
        if (g == 0) { c = 1.f; sn = 0.f; }
        else { sn = ang[(g-1)*2 + 0]; c = ang[(g-1)*2 + 1]; }
#pragma unroll
        for (int i = 0; i < 3; i++) {
            float d0 = df[i*4+0], d1 = df[i*4+1], d2 = df[i*4+2];
            fr[g][i*3+0] = d0;
            fr[g][i*3+1] = d1*c + d2*sn;
            fr[g][i*3+2] = d2*c - d1*sn;
            ft[g][i] = df[i*4+3];
        }
    }
#pragma unroll
    for (int g = 5; g <= 7; g++) {
        float r[9], t[3];
        const float* r1 = fr[g-1];
        const float* t1 = ft[g-1];
#pragma unroll
        for (int i = 0; i < 3; i++) {
#pragma unroll
            for (int j = 0; j < 3; j++)
                r[i*3+j] = r1[i*3+0]*fr[g][0*3+j] + r1[i*3+1]*fr[g][1*3+j] + r1[i*3+2]*fr[g][2*3+j];
            t[i] = r1[i*3+0]*ft[g][0] + r1[i*3+1]*ft[g][1] + r1[i*3+2]*ft[g][2] + t1[i];
        }
#pragma unroll
        for (int i = 0; i < 9; i++) fr[g][i] = r[i];
#pragma unroll
        for (int i = 0; i < 3; i++) ft[g][i] = t[i];
    }
#pragma unroll
    for (int g = 0; g < 8; g++) {
        float r[9], t[3];
#pragma unroll
        for (int i = 0; i < 3; i++) {
#pragma unroll
            for (int j = 0; j < 3; j++)
                r[i*3+j] = rb[i*3+0]*fr[g][0*3+j] + rb[i*3+1]*fr[g][1*3+j] + rb[i*3+2]*fr[g][2*3+j];
            t[i] = rb[i*3+0]*ft[g][0] + rb[i*3+1]*ft[g][1] + rb[i*3+2]*ft[g][2];
        }
#pragma unroll
        for (int i = 0; i < 9; i++) fr[g][i] = r[i];
        ft[g][0]=t[0]+tbx; ft[g][1]=t[1]+tby; ft[g][2]=t[2]+tbz;
    }
#pragma unroll
    for (int g = 0; g < 8; g++) {
#pragma unroll
        for (int a = 0; a < 14; a++) {
            if (sgi[s*14 + a] == g) {
                float m  = sm14[s*14 + a];
                float lx = slit[(s*14 + a)*3 + 0];
                float ly = slit[(s*14 + a)*3 + 1];
                float lz = slit[(s*14 + a)*3 + 2];
                float px = (fr[g][0]*lx + fr[g][1]*ly + fr[g][2]*lz + ft[g][0]) * m;
                float py = (fr[g][3]*lx + fr[g][4]*ly + fr[g][5]*lz + ft[g][1]) * m;
                float pz = (fr[g][6]*lx + fr[g][7]*ly + fr[g][8]*lz + ft[g][2]) * m;
                predL[threadIdx.x][a*3+0] = px;
                predL[threadIdx.x][a*3+1] = py;
                predL[threadIdx.x][a*3+2] = pz;
                out_pred[((size_t)p*14 + a)*3 + 0] = px;
                out_pred[((size_t)p*14 + a)*3 + 1] = py;
                out_pred[((size_t)p*14 + a)*3 + 2] = pz;
            }
        }
    }
#pragma unroll
    for (int a = 0; a < 14; a++) out_m14[(size_t)p*14 + a] = sm14[s*14 + a];

    const int* idx = residx + (size_t)p * 37;
#pragma unroll
    for (int a = 0; a < 37; a++) {
        int id = idx[a];
        out_final[((size_t)p*37 + a)*3 + 0] = predL[threadIdx.x][id*3+0];
        out_final[((size_t)p*37 + a)*3 + 1] = predL[threadIdx.x][id*3+1];
        out_final[((size_t)p*37 + a)*3 + 2] = predL[threadIdx.x][id*3+2];
        out_m37[(size_t)p*37 + a] = sm37[s*37 + a];
    }
}

extern "C" void kernel_launch(void* const* d_in, const int* in_sizes, int n_in,
                              void* d_out, int out_size, void* d_ws, size_t ws_size,
                              hipStream_t stream) {
    const float* act        = (const float*)d_in[0];
    const float* angles     = (const float*)d_in[1];
    const float* rigids     = (const float*)d_in[2];
    const int*   fixed_mask = (const int*)d_in[3];
    const int*   seq_t      = (const int*)d_in[4];
    const int*   residx     = (const int*)d_in[5];
    const float* lng        = (const float*)d_in[6];
    const float* lnb        = (const float*)d_in[7];
    const float* w1         = (const float*)d_in[8];
    const float* b1         = (const float*)d_in[9];
    const float* w2         = (const float*)d_in[10];
    const float* b2         = (const float*)d_in[11];
    const float* w3         = (const float*)d_in[12];
    const float* b3         = (const float*)d_in[13];
    const float* dfr        = (const float*)d_in[14];
    const int*   gidx       = (const int*)d_in[15];
    const float* a14m       = (const float*)d_in[16];
    const float* a37m       = (const float*)d_in[17];
    const float* litp       = (const float*)d_in[18];

    float* out        = (float*)d_out;
    float* out_logits = out;
    float* out_seq    = out_logits + (size_t)M_TOTAL * NRES;
    float* out_pred   = out_seq    + (size_t)M_TOTAL;
    float* out_final  = out_pred   + (size_t)M_TOTAL * 42;
    float* out_m14    = out_final  + (size_t)M_TOTAL * 111;
    float* out_m37    = out_m14    + (size_t)M_TOTAL * 14;

    char* wsp = (char*)d_ws;
    int*   seq0i = (int*)wsp;   wsp += (size_t)M_TOTAL * sizeof(int);
    float* mu    = (float*)wsp; wsp += (size_t)M_TOTAL * sizeof(float);
    float* rstd  = (float*)wsp; wsp += (size_t)M_TOTAL * sizeof(float);
    short* w1h   = (short*)wsp; wsp += (size_t)H_ * C_ * sizeof(short);
    short* w1l   = (short*)wsp; wsp += (size_t)H_ * C_ * sizeof(short);
    short* w2h   = (short*)wsp; wsp += (size_t)H_ * H_ * sizeof(short);
    short* w2l   = (short*)wsp; wsp += (size_t)H_ * H_ * sizeof(short);
    short* w3h   = (short*)wsp; wsp += (size_t)128 * H_ * sizeof(short);
    short* w3l   = (short*)wsp; wsp += (size_t)128 * H_ * sizeof(short);

    size_t fixed_bytes = (size_t)(wsp - (char*)d_ws);
    size_t per_row = 4ull * H_ * sizeof(short) + (size_t)KSPLIT * 32 * sizeof(float);
    int chunkM = 4096;
    if (ws_size - fixed_bytes >= (size_t)M_TOTAL * per_row)      chunkM = M_TOTAL;
    else if (ws_size - fixed_bytes >= (size_t)16384 * per_row)   chunkM = 16384;
    else if (ws_size - fixed_bytes >= (size_t)8192 * per_row)    chunkM = 8192;

    short* H1h = (short*)wsp; wsp += (size_t)chunkM * H_ * sizeof(short);
    short* H1l = (short*)wsp; wsp += (size_t)chunkM * H_ * sizeof(short);
    short* H2h = (short*)wsp; wsp += (size_t)chunkM * H_ * sizeof(short);
    short* H2l = (short*)wsp; wsp += (size_t)chunkM * H_ * sizeof(short);
    float* part = (float*)wsp;

    conv_w_kernel<<<dim3(H_/32, C_/32), 256, 0, stream>>>(w1, w1h, w1l, C_, H_, H_);
    conv_w_kernel<<<dim3(H_/32, H_/32), 256, 0, stream>>>(w2, w2h, w2l, H_, H_, H_);
    conv_w_kernel<<<dim3(128/32, H_/32), 256, 0, stream>>>(w3, w3h, w3l, H_, NRES, 128);

    ln_stats_kernel<<<M_TOTAL/4, 256, 0, stream>>>(act, mu, rstd);

    for (int c = 0; c < M_TOTAL / chunkM; c++) {
        int m0 = c * chunkM;
        // GEMM1: grid x = row tiles (same-A -> same XCD)
        mlp_gemm1<<<dim3(chunkM/BM, H_/BN), 256, 0, stream>>>(
            act + (size_t)m0 * C_, w1h, w1l, b1, H1h, H1l, C_, H_,
            mu + m0, rstd + m0, lng, lnb);
        // GEMM2: 128x128 m97-structure tile
        mlp_gemm2_128<<<dim3(chunkM/128, H_/128), 256, 0, stream>>>(
            H1h, H1l, w2h, w2l, b2, H2h, H2l, H_, H_);
        gemm3_partial<<<dim3(KSPLIT, chunkM/128), 256, 0, stream>>>(H2h, H2l, w3h, w3l,
                                                                    part, chunkM);
        logits_argmax<<<chunkM/256, 256, 0, stream>>>(part, chunkM, m0, b3,
                                                      fixed_mask, seq_t,
                                                      out_logits, out_seq, seq0i);
    }

    geom_kernel<<<M_TOTAL/128, 128, 0, stream>>>(angles, rigids, seq0i, residx,
                                                 dfr, gidx, a14m, a37m, litp,
                                                 out_pred, out_final, out_m14, out_m37);
}

// Round 6
// 548.241 us; speedup vs baseline: 3.8973x; 1.0629x over previous
//
#include <hip/hip_runtime.h>
#include <math.h>

#define B_ 32
#define N_ 1024
#define C_ 384
#define H_ 1024
#define NRES 20
#define NTAB 21
#define M_TOTAL (B_*N_)   // 32768

#define BM 64
#define BN 128
#define BK 32
#define LDK 40   // LDS row stride for the LN-fused GEMM1 (padded, VGPR-staged)
#define KSPLIT 8

typedef __attribute__((ext_vector_type(8))) short bf16x8;
typedef __attribute__((ext_vector_type(4))) float f32x4;

#define GLOAD_LDS(gptr, lptr) \
    __builtin_amdgcn_global_load_lds( \
        (const __attribute__((address_space(1))) void*)(gptr), \
        (__attribute__((address_space(3))) void*)(lptr), 16, 0, 0)

__device__ inline short bf16_rne(float v) {
    unsigned u = __float_as_uint(v);
    unsigned r = u + 0x7fffu + ((u >> 16) & 1u);
    return (short)(r >> 16);
}
// v ~= hi + lo, each bf16 (RNE). ~16 mantissa bits captured.
__device__ inline void split2(float v, short& h, short& l) {
    unsigned u = __float_as_uint(v);
    unsigned r = (u + 0x7fffu + ((u >> 16) & 1u)) & 0xffff0000u;
    h = (short)(r >> 16);
    l = bf16_rne(v - __uint_as_float(r));
}

// ---------------- LN row stats: one wave per row ----------------
__global__ __launch_bounds__(256) void ln_stats_kernel(const float* __restrict__ act,
                                                       float* __restrict__ mu_out,
                                                       float* __restrict__ rstd_out) {
    int wave = threadIdx.x >> 6;
    int lane = threadIdx.x & 63;
    int row  = blockIdx.x * 4 + wave;
    const float* x = act + (size_t)row * C_;
    float v[6];
    float s = 0.f;
#pragma unroll
    for (int i = 0; i < 6; i++) { v[i] = x[lane + i*64]; s += v[i]; }
#pragma unroll
    for (int off = 32; off > 0; off >>= 1) s += __shfl_xor(s, off, 64);
    float mu = s * (1.0f/384.0f);
    float vs = 0.f;
#pragma unroll
    for (int i = 0; i < 6; i++) { float d = v[i]-mu; vs += d*d; }
#pragma unroll
    for (int off = 32; off > 0; off >>= 1) vs += __shfl_xor(vs, off, 64);
    float var = vs * (1.0f/384.0f);
    if (lane == 0) { mu_out[row] = mu; rstd_out[row] = 1.0f / sqrtf(var + 1e-5f); }
}

// ---------------- weight transpose + split-bf16 convert ----------------
__global__ __launch_bounds__(256) void conv_w_kernel(const float* __restrict__ w,
                                                     short* __restrict__ th,
                                                     short* __restrict__ tl,
                                                     int K, int N, int Npad) {
    __shared__ float t[32][33];
    int n0 = blockIdx.x * 32, k0 = blockIdx.y * 32;
    int tx = threadIdx.x & 31, ty = threadIdx.x >> 5;
#pragma unroll
    for (int i = ty; i < 32; i += 8) {
        int k = k0 + i, n = n0 + tx;
        t[i][tx] = (n < N) ? w[(size_t)k * N + n] : 0.f;
    }
    __syncthreads();
#pragma unroll
    for (int i = ty; i < 32; i += 8) {
        int n = n0 + i, k = k0 + tx;
        short h, l; split2(t[tx][i], h, l);
        th[(size_t)n * K + k] = h;
        tl[(size_t)n * K + k] = l;
    }
}

// ---------------- GEMM1: LN-fused split-bf16 MFMA, 64x128 tile ----------------
// grid: (chunkM/BM, H/BN) -- x = row tiles (same-A blocks land on same XCD)
__global__ __launch_bounds__(256) void mlp_gemm1(
    const float* __restrict__ A32,
    const short* __restrict__ BTh, const short* __restrict__ BTl,
    const float* __restrict__ bias,
    short* __restrict__ Ch, short* __restrict__ Cl,
    int K, int ldc,
    const float* __restrict__ mu, const float* __restrict__ rstd,
    const float* __restrict__ lng, const float* __restrict__ lnb)
{
    __shared__ short Ah[BM][LDK], Al[BM][LDK];
    __shared__ short Bh[BN][LDK], Bl[BN][LDK];
    int tid = threadIdx.x;
    int m0 = blockIdx.x * BM;
    int n0 = blockIdx.y * BN;
    int lane = tid & 63, wv = tid >> 6;
    int wm = (wv & 1) * 32, wn = (wv >> 1) * 64;
    int fm = lane & 15, kg = lane >> 4;

    f32x4 acc[2][4] = {};

    int br = tid >> 2;          // 0..63
    int bk8 = (tid & 3) * 8;
    int ar = tid >> 3;          // 0..31
    int ak = (tid & 7) * 4;
    float mur[2], rsr[2];
#pragma unroll
    for (int p = 0; p < 2; p++) { mur[p] = mu[m0 + ar + p*32]; rsr[p] = rstd[m0 + ar + p*32]; }

    for (int k0 = 0; k0 < K; k0 += BK) {
#pragma unroll
        for (int p = 0; p < 2; p++) {
            int row = m0 + ar + p * 32;
            float4 v = *(const float4*)&A32[(size_t)row * K + k0 + ak];
            float4 g = *(const float4*)&lng[k0 + ak];
            float4 b = *(const float4*)&lnb[k0 + ak];
            v.x = (v.x - mur[p]) * rsr[p] * g.x + b.x;
            v.y = (v.y - mur[p]) * rsr[p] * g.y + b.y;
            v.z = (v.z - mur[p]) * rsr[p] * g.z + b.z;
            v.w = (v.w - mur[p]) * rsr[p] * g.w + b.w;
            short4 h4, l4;
            split2(v.x, h4.x, l4.x);
            split2(v.y, h4.y, l4.y);
            split2(v.z, h4.z, l4.z);
            split2(v.w, h4.w, l4.w);
            *(short4*)&Ah[ar + p*32][ak] = h4;
            *(short4*)&Al[ar + p*32][ak] = l4;
        }
#pragma unroll
        for (int p = 0; p < 2; p++) {
            int row = n0 + br + p * 64;
            int4 vh = *(const int4*)&BTh[(size_t)row * K + k0 + bk8];
            int4 vl = *(const int4*)&BTl[(size_t)row * K + k0 + bk8];
            *(int4*)&Bh[br + p*64][bk8] = vh;
            *(int4*)&Bl[br + p*64][bk8] = vl;
        }
        __syncthreads();

        bf16x8 a_h[2], a_l[2], b_h[4], b_l[4];
#pragma unroll
        for (int i = 0; i < 2; i++) {
            a_h[i] = *(bf16x8*)&Ah[wm + i*16 + fm][kg*8];
            a_l[i] = *(bf16x8*)&Al[wm + i*16 + fm][kg*8];
        }
#pragma unroll
        for (int j = 0; j < 4; j++) {
            b_h[j] = *(bf16x8*)&Bh[wn + j*16 + fm][kg*8];
            b_l[j] = *(bf16x8*)&Bl[wn + j*16 + fm][kg*8];
        }
#pragma unroll
        for (int i = 0; i < 2; i++)
#pragma unroll
            for (int j = 0; j < 4; j++) {
                f32x4 c = acc[i][j];
                c = __builtin_amdgcn_mfma_f32_16x16x32_bf16(a_l[i], b_h[j], c, 0, 0, 0);
                c = __builtin_amdgcn_mfma_f32_16x16x32_bf16(a_h[i], b_l[j], c, 0, 0, 0);
                c = __builtin_amdgcn_mfma_f32_16x16x32_bf16(a_h[i], b_h[j], c, 0, 0, 0);
                acc[i][j] = c;
            }
        __syncthreads();
    }

#pragma unroll
    for (int i = 0; i < 2; i++)
#pragma unroll
        for (int j = 0; j < 4; j++) {
            int col = n0 + wn + j*16 + fm;
            float bs = bias[col];
#pragma unroll
            for (int r = 0; r < 4; r++) {
                int row = m0 + wm + i*16 + kg*4 + r;
                float v = fmaxf(acc[i][j][r] + bs, 0.f);
                short h, l; split2(v, h, l);
                Ch[(size_t)row * ldc + col] = h;
                Cl[(size_t)row * ldc + col] = l;
            }
        }
}

// ---------------- GEMM2: pre-split planes, 128x128 tile, global_load_lds staging ----
// Unpadded LDS [128][32] (global_load_lds needs contiguous lane order).
// Wave w stages plane w (Ah/Al/Bh/Bl) with 8 width-16 calls per k-iter.
// grid: (chunkM/128, H/128) -- x = row tiles
__global__ __launch_bounds__(256) void presplit_gemm128(
    const short* __restrict__ Ahg, const short* __restrict__ Alg,
    const short* __restrict__ BTh, const short* __restrict__ BTl,
    const float* __restrict__ bias,
    short* __restrict__ Ch, short* __restrict__ Cl,
    int K, int ldc)
{
    __shared__ short Ah[128][32], Al[128][32], Bh[128][32], Bl[128][32];
    int tid = threadIdx.x;
    int m0 = blockIdx.x * 128;
    int n0 = blockIdx.y * 128;
    int lane = tid & 63, wv = tid >> 6;
    int wm = (wv & 1) * 64, wn = (wv >> 1) * 64;
    int fm = lane & 15, kg = lane >> 4;

    // staging role: wave wv owns one plane
    const short* gsrc = (wv == 0) ? Ahg : (wv == 1) ? Alg : (wv == 2) ? BTh : BTl;
    short* lbase = (wv == 0) ? &Ah[0][0] : (wv == 1) ? &Al[0][0]
                 : (wv == 2) ? &Bh[0][0] : &Bl[0][0];
    int base = (wv < 2) ? m0 : n0;
    // lane covers row = base + c*16 + (lane>>2), cols (lane&3)*8 .. +8
    const short* gp = gsrc + (size_t)(base + (lane >> 2)) * K + (lane & 3) * 8;

    f32x4 acc[4][4] = {};

    for (int k0 = 0; k0 < K; k0 += BK) {
#pragma unroll
        for (int c = 0; c < 8; c++)
            GLOAD_LDS(gp + (size_t)(c * 16) * K + k0, lbase + c * 512);
        __syncthreads();

        bf16x8 a_h[4], a_l[4], b_h[4], b_l[4];
#pragma unroll
        for (int i = 0; i < 4; i++) {
            a_h[i] = *(bf16x8*)&Ah[wm + i*16 + fm][kg*8];
            a_l[i] = *(bf16x8*)&Al[wm + i*16 + fm][kg*8];
            b_h[i] = *(bf16x8*)&Bh[wn + i*16 + fm][kg*8];
            b_l[i] = *(bf16x8*)&Bl[wn + i*16 + fm][kg*8];
        }
#pragma unroll
        for (int i = 0; i < 4; i++)
#pragma unroll
            for (int j = 0; j < 4; j++) {
                f32x4 c = acc[i][j];
                c = __builtin_amdgcn_mfma_f32_16x16x32_bf16(a_l[i], b_h[j], c, 0, 0, 0);
                c = __builtin_amdgcn_mfma_f32_16x16x32_bf16(a_h[i], b_l[j], c, 0, 0, 0);
                c = __builtin_amdgcn_mfma_f32_16x16x32_bf16(a_h[i], b_h[j], c, 0, 0, 0);
                acc[i][j] = c;
            }
        __syncthreads();
    }

#pragma unroll
    for (int i = 0; i < 4; i++)
#pragma unroll
        for (int j = 0; j < 4; j++) {
            int col = n0 + wn + j*16 + fm;
            float bs = bias[col];
#pragma unroll
            for (int r = 0; r < 4; r++) {
                int row = m0 + wm + i*16 + kg*4 + r;
                float v = fmaxf(acc[i][j][r] + bs, 0.f);
                short h, l; split2(v, h, l);
                Ch[(size_t)row * ldc + col] = h;
                Cl[(size_t)row * ldc + col] = l;
            }
        }
}

// ---------------- GEMM3 split-K partial, global_load_lds staging ----------------
// A tile 128x32 (waves 0-1 stage hi/lo), B tile 32x32 (waves 2-3 stage hi/lo).
__global__ __launch_bounds__(256) void gemm3_partial(
    const short* __restrict__ Ahg, const short* __restrict__ Alg,   // H2 planes, [M][1024]
    const short* __restrict__ BTh, const short* __restrict__ BTl,   // w3 planes, [128][1024]
    float* __restrict__ partial, int chunkM)
{
    __shared__ short Ah[128][32], Al[128][32];
    __shared__ short Bh[32][32], Bl[32][32];
    int tid = threadIdx.x;
    int kbase = blockIdx.x * 128;
    int m0 = blockIdx.y * 128;
    int lane = tid & 63, wv = tid >> 6;
    int wm = wv * 32;
    int fm = lane & 15, kg = lane >> 4;

    const short* gsrc = (wv == 0) ? Ahg : (wv == 1) ? Alg : (wv == 2) ? BTh : BTl;
    short* lbase = (wv == 0) ? &Ah[0][0] : (wv == 1) ? &Al[0][0]
                 : (wv == 2) ? &Bh[0][0] : &Bl[0][0];
    int base = (wv < 2) ? m0 : 0;
    int ncalls = (wv < 2) ? 8 : 2;
    const short* gp = gsrc + (size_t)(base + (lane >> 2)) * H_ + (lane & 3) * 8;

    f32x4 acc[2][2] = {};

    for (int k0 = kbase; k0 < kbase + 128; k0 += BK) {
        for (int c = 0; c < ncalls; c++)
            GLOAD_LDS(gp + (size_t)(c * 16) * H_ + k0, lbase + c * 512);
        __syncthreads();

        bf16x8 a_h[2], a_l[2], b_h[2], b_l[2];
#pragma unroll
        for (int i = 0; i < 2; i++) {
            a_h[i] = *(bf16x8*)&Ah[wm + i*16 + fm][kg*8];
            a_l[i] = *(bf16x8*)&Al[wm + i*16 + fm][kg*8];
        }
#pragma unroll
        for (int j = 0; j < 2; j++) {
            b_h[j] = *(bf16x8*)&Bh[j*16 + fm][kg*8];
            b_l[j] = *(bf16x8*)&Bl[j*16 + fm][kg*8];
        }
#pragma unroll
        for (int i = 0; i < 2; i++)
#pragma unroll
            for (int j = 0; j < 2; j++) {
                f32x4 c = acc[i][j];
                c = __builtin_amdgcn_mfma_f32_16x16x32_bf16(a_l[i], b_h[j], c, 0, 0, 0);
                c = __builtin_amdgcn_mfma_f32_16x16x32_bf16(a_h[i], b_l[j], c, 0, 0, 0);
                c = __builtin_amdgcn_mfma_f32_16x16x32_bf16(a_h[i], b_h[j], c, 0, 0, 0);
                acc[i][j] = c;
            }
        __syncthreads();
    }

    float* pp = partial + (size_t)blockIdx.x * chunkM * 32;
#pragma unroll
    for (int i = 0; i < 2; i++)
#pragma unroll
        for (int j = 0; j < 2; j++) {
            int col = j*16 + fm;
#pragma unroll
            for (int r = 0; r < 4; r++) {
                int row = m0 + wm + i*16 + kg*4 + r;
                pp[(size_t)row * 32 + col] = acc[i][j][r];
            }
        }
}

// ---------------- logits reduce + bias + argmax + fixed-mask merge ----------------
__global__ __launch_bounds__(256) void logits_argmax(
    const float* __restrict__ partial, int chunkM, int m0,
    const float* __restrict__ b3,
    const int* __restrict__ fixed_mask, const int* __restrict__ seq_t,
    float* __restrict__ out_logits, float* __restrict__ seq_out,
    int* __restrict__ seq_int)
{
    int rl = blockIdx.x * blockDim.x + threadIdx.x;    // chunk-local row
    int row = m0 + rl;
    float best = -1e30f; int bi = 0;
    float* lg = out_logits + (size_t)row * NRES;
#pragma unroll 4
    for (int n = 0; n < NRES; n++) {
        float s = b3[n];
#pragma unroll
        for (int p = 0; p < KSPLIT; p++)
            s += partial[((size_t)p * chunkM + rl) * 32 + n];
        lg[n] = s;
        if (s > best) { best = s; bi = n; }
    }
    int fm = fixed_mask[row];
    int s = fm ? seq_t[row] : bi;
    seq_int[row] = s;
    seq_out[row] = (float)s;
}

// ---------------- geometry: one thread per (b,n) ----------------
__global__ __launch_bounds__(128) void geom_kernel(
    const float* __restrict__ angles, const float* __restrict__ rigids,
    const int* __restrict__ seq0i, const int* __restrict__ residx,
    const float* __restrict__ dframes, const int* __restrict__ gidx,
    const float* __restrict__ a14m, const float* __restrict__ a37m,
    const float* __restrict__ litp,
    float* __restrict__ out_pred, float* __restrict__ out_final,
    float* __restrict__ out_m14, float* __restrict__ out_m37)
{
    __shared__ float sdf[NTAB*8*16];
    __shared__ int   sgi[NTAB*14];
    __shared__ float sm14[NTAB*14];
    __shared__ float sm37[NTAB*37];
    __shared__ float slit[NTAB*14*3];
    __shared__ float predL[128][43];

    for (int i = threadIdx.x; i < NTAB*128; i += 128) sdf[i] = dframes[i];
    for (int i = threadIdx.x; i < NTAB*14; i += 128) { sgi[i] = gidx[i]; sm14[i] = a14m[i]; }
    for (int i = threadIdx.x; i < NTAB*37; i += 128) sm37[i] = a37m[i];
    for (int i = threadIdx.x; i < NTAB*42; i += 128) slit[i] = litp[i];
    __syncthreads();

    int p = blockIdx.x * 128 + threadIdx.x;
    int s = seq0i[p];

    const float* rg = rigids + (size_t)p * 7;
    float qw = rg[0], qx = rg[1], qy = rg[2], qz = rg[3];
    float tbx = rg[4], tby = rg[5], tbz = rg[6];
    float qn = 1.0f / sqrtf(qw*qw + qx*qx + qy*qy + qz*qz + 1e-8f);
    qw *= qn; qx *= qn; qy *= qn; qz *= qn;
    float rb[9];
    rb[0] = 1.f - 2.f*(qy*qy + qz*qz); rb[1] = 2.f*(qx*qy - qw*qz); rb[2] = 2.f*(qx*qz + qw*qy);
    rb[3] = 2.f*(qx*qy + qw*qz); rb[4] = 1.f - 2.f*(qx*qx + qz*qz); rb[5] = 2.f*(qy*qz - qw*qx);
    rb[6] = 2.f*(qx*qz - qw*qy); rb[7] = 2.f*(qy*qz + qw*qx); rb[8] = 1.f - 2.f*(qx*qx + qy*qy);

    float fr[8][9], ft[8][3];
    const float* ang = angles + (size_t)p * 14;
#pragma unroll
    for (int g = 0; g < 8; g++) {
        const float* df = &sdf[(s*8 + g)*16];
        float c, sn;
        if (g == 0) { c = 1.f; sn = 0.f; }
        else { sn = ang[(g-1)*2 + 0]; c = ang[(g-1)*2 + 1]; }
#pragma unroll
        for (int i = 0; i < 3; i++) {
            float d0 = df[i*4+0], d1 = df[i*4+1], d2 = df[i*4+2];
            fr[g][i*3+0] = d0;
            fr[g][i*3+1] = d1*c + d2*sn;
            fr[g][i*3+2] = d2*c - d1*sn;
            ft[g][i] = df[i*4+3];
        }
    }
#pragma unroll
    for (int g = 5; g <= 7; g++) {
        float r[9], t[3];
        const float* r1 = fr[g-1];
        const float* t1 = ft[g-1];
#pragma unroll
        for (int i = 0; i < 3; i++) {
#pragma unroll
            for (int j = 0; j < 3; j++)
                r[i*3+j] = r1[i*3+0]*fr[g][0*3+j] + r1[i*3+1]*fr[g][1*3+j] + r1[i*3+2]*fr[g][2*3+j];
            t[i] = r1[i*3+0]*ft[g][0] + r1[i*3+1]*ft[g][1] + r1[i*3+2]*ft[g][2] + t1[i];
        }
#pragma unroll
        for (int i = 0; i < 9; i++) fr[g][i] = r[i];
#pragma unroll
        for (int i = 0; i < 3; i++) ft[g][i] = t[i];
    }
#pragma unroll
    for (int g = 0; g < 8; g++) {
        float r[9], t[3];
#pragma unroll
        for (int i = 0; i < 3; i++) {
#pragma unroll
            for (int j = 0; j < 3; j++)
                r[i*3+j] = rb[i*3+0]*fr[g][0*3+j] + rb[i*3+1]*fr[g][1*3+j] + rb[i*3+2]*fr[g][2*3+j];
            t[i] = rb[i*3+0]*ft[g][0] + rb[i*3+1]*ft[g][1] + rb[i*3+2]*ft[g][2];
        }
#pragma unroll
        for (int i = 0; i < 9; i++) fr[g][i] = r[i];
        ft[g][0]=t[0]+tbx; ft[g][1]=t[1]+tby; ft[g][2]=t[2]+tbz;
    }
#pragma unroll
    for (int g = 0; g < 8; g++) {
#pragma unroll
        for (int a = 0; a < 14; a++) {
            if (sgi[s*14 + a] == g) {
                float m  = sm14[s*14 + a];
                float lx = slit[(s*14 + a)*3 + 0];
                float ly = slit[(s*14 + a)*3 + 1];
                float lz = slit[(s*14 + a)*3 + 2];
                float px = (fr[g][0]*lx + fr[g][1]*ly + fr[g][2]*lz + ft[g][0]) * m;
                float py = (fr[g][3]*lx + fr[g][4]*ly + fr[g][5]*lz + ft[g][1]) * m;
                float pz = (fr[g][6]*lx + fr[g][7]*ly + fr[g][8]*lz + ft[g][2]) * m;
                predL[threadIdx.x][a*3+0] = px;
                predL[threadIdx.x][a*3+1] = py;
                predL[threadIdx.x][a*3+2] = pz;
                out_pred[((size_t)p*14 + a)*3 + 0] = px;
                out_pred[((size_t)p*14 + a)*3 + 1] = py;
                out_pred[((size_t)p*14 + a)*3 + 2] = pz;
            }
        }
    }
#pragma unroll
    for (int a = 0; a < 14; a++) out_m14[(size_t)p*14 + a] = sm14[s*14 + a];

    const int* idx = residx + (size_t)p * 37;
#pragma unroll
    for (int a = 0; a < 37; a++) {
        int id = idx[a];
        out_final[((size_t)p*37 + a)*3 + 0] = predL[threadIdx.x][id*3+0];
        out_final[((size_t)p*37 + a)*3 + 1] = predL[threadIdx.x][id*3+1];
        out_final[((size_t)p*37 + a)*3 + 2] = predL[threadIdx.x][id*3+2];
        out_m37[(size_t)p*37 + a] = sm37[s*37 + a];
    }
}

extern "C" void kernel_launch(void* const* d_in, const int* in_sizes, int n_in,
                              void* d_out, int out_size, void* d_ws, size_t ws_size,
                              hipStream_t stream) {
    const float* act        = (const float*)d_in[0];
    const float* angles     = (const float*)d_in[1];
    const float* rigids     = (const float*)d_in[2];
    const int*   fixed_mask = (const int*)d_in[3];
    const int*   seq_t      = (const int*)d_in[4];
    const int*   residx     = (const int*)d_in[5];
    const float* lng        = (const float*)d_in[6];
    const float* lnb        = (const float*)d_in[7];
    const float* w1         = (const float*)d_in[8];
    const float* b1         = (const float*)d_in[9];
    const float* w2         = (const float*)d_in[10];
    const float* b2         = (const float*)d_in[11];
    const float* w3         = (const float*)d_in[12];
    const float* b3         = (const float*)d_in[13];
    const float* dfr        = (const float*)d_in[14];
    const int*   gidx       = (const int*)d_in[15];
    const float* a14m       = (const float*)d_in[16];
    const float* a37m       = (const float*)d_in[17];
    const float* litp       = (const float*)d_in[18];

    float* out        = (float*)d_out;
    float* out_logits = out;
    float* out_seq    = out_logits + (size_t)M_TOTAL * NRES;
    float* out_pred   = out_seq    + (size_t)M_TOTAL;
    float* out_final  = out_pred   + (size_t)M_TOTAL * 42;
    float* out_m14    = out_final  + (size_t)M_TOTAL * 111;
    float* out_m37    = out_m14    + (size_t)M_TOTAL * 14;

    char* wsp = (char*)d_ws;
    int*   seq0i = (int*)wsp;   wsp += (size_t)M_TOTAL * sizeof(int);
    float* mu    = (float*)wsp; wsp += (size_t)M_TOTAL * sizeof(float);
    float* rstd  = (float*)wsp; wsp += (size_t)M_TOTAL * sizeof(float);
    short* w1h   = (short*)wsp; wsp += (size_t)H_ * C_ * sizeof(short);
    short* w1l   = (short*)wsp; wsp += (size_t)H_ * C_ * sizeof(short);
    short* w2h   = (short*)wsp; wsp += (size_t)H_ * H_ * sizeof(short);
    short* w2l   = (short*)wsp; wsp += (size_t)H_ * H_ * sizeof(short);
    short* w3h   = (short*)wsp; wsp += (size_t)128 * H_ * sizeof(short);
    short* w3l   = (short*)wsp; wsp += (size_t)128 * H_ * sizeof(short);

    size_t fixed_bytes = (size_t)(wsp - (char*)d_ws);
    size_t per_row = 4ull * H_ * sizeof(short) + (size_t)KSPLIT * 32 * sizeof(float);
    int chunkM = 4096;
    if (ws_size - fixed_bytes >= (size_t)M_TOTAL * per_row)      chunkM = M_TOTAL;
    else if (ws_size - fixed_bytes >= (size_t)16384 * per_row)   chunkM = 16384;
    else if (ws_size - fixed_bytes >= (size_t)8192 * per_row)    chunkM = 8192;

    short* H1h = (short*)wsp; wsp += (size_t)chunkM * H_ * sizeof(short);
    short* H1l = (short*)wsp; wsp += (size_t)chunkM * H_ * sizeof(short);
    short* H2h = (short*)wsp; wsp += (size_t)chunkM * H_ * sizeof(short);
    short* H2l = (short*)wsp; wsp += (size_t)chunkM * H_ * sizeof(short);
    float* part = (float*)wsp;

    conv_w_kernel<<<dim3(H_/32, C_/32), 256, 0, stream>>>(w1, w1h, w1l, C_, H_, H_);
    conv_w_kernel<<<dim3(H_/32, H_/32), 256, 0, stream>>>(w2, w2h, w2l, H_, H_, H_);
    conv_w_kernel<<<dim3(128/32, H_/32), 256, 0, stream>>>(w3, w3h, w3l, H_, NRES, 128);

    ln_stats_kernel<<<M_TOTAL/4, 256, 0, stream>>>(act, mu, rstd);

    for (int c = 0; c < M_TOTAL / chunkM; c++) {
        int m0 = c * chunkM;
        // GEMM1: grid x = row tiles (same-A -> same XCD)
        mlp_gemm1<<<dim3(chunkM/BM, H_/BN), 256, 0, stream>>>(
            act + (size_t)m0 * C_, w1h, w1l, b1, H1h, H1l, C_, H_,
            mu + m0, rstd + m0, lng, lnb);
        // GEMM2: 128x128 tile, global_load_lds staging
        presplit_gemm128<<<dim3(chunkM/128, H_/128), 256, 0, stream>>>(
            H1h, H1l, w2h, w2l, b2, H2h, H2l, H_, H_);
        gemm3_partial<<<dim3(KSPLIT, chunkM/128), 256, 0, stream>>>(H2h, H2l, w3h, w3l,
                                                                    part, chunkM);
        logits_argmax<<<chunkM/256, 256, 0, stream>>>(part, chunkM, m0, b3,
                                                      fixed_mask, seq_t,
                                                      out_logits, out_seq, seq0i);
    }

    geom_kernel<<<M_TOTAL/128, 128, 0, stream>>>(angles, rigids, seq0i, residx,
                                                 dfr, gidx, a14m, a37m, litp,
                                                 out_pred, out_final, out_m14, out_m37);
}

// Round 7
// 539.201 us; speedup vs baseline: 3.9626x; 1.0168x over previous
//
#include <hip/hip_runtime.h>
#include <math.h>

#define B_ 32
#define N_ 1024
#define C_ 384
#define H_ 1024
#define NRES 20
#define NTAB 21
#define M_TOTAL (B_*N_)   // 32768
#define BK 32

typedef __attribute__((ext_vector_type(8))) short bf16x8;
typedef __attribute__((ext_vector_type(4))) float f32x4;

#define GLOAD_LDS(gptr, lptr) \
    __builtin_amdgcn_global_load_lds( \
        (const __attribute__((address_space(1))) void*)(gptr), \
        (__attribute__((address_space(3))) void*)(lptr), 16, 0, 0)

__device__ inline short bf16_rne(float v) {
    unsigned u = __float_as_uint(v);
    unsigned r = u + 0x7fffu + ((u >> 16) & 1u);
    return (short)(r >> 16);
}
// v ~= hi + lo, each bf16 (RNE). ~16 mantissa bits captured.
__device__ inline void split2(float v, short& h, short& l) {
    unsigned u = __float_as_uint(v);
    unsigned r = (u + 0x7fffu + ((u >> 16) & 1u)) & 0xffff0000u;
    h = (short)(r >> 16);
    l = bf16_rne(v - __uint_as_float(r));
}

// ---------------- LN + split: one wave per row, full M ----------------
__global__ __launch_bounds__(256) void ln_split_kernel(const float* __restrict__ act,
                                                       const float* __restrict__ lng,
                                                       const float* __restrict__ lnb,
                                                       short* __restrict__ Xh,
                                                       short* __restrict__ Xl) {
    int wave = threadIdx.x >> 6;
    int lane = threadIdx.x & 63;
    int row  = blockIdx.x * 4 + wave;
    const float* x = act + (size_t)row * C_;
    float v[6];
    float s = 0.f;
#pragma unroll
    for (int i = 0; i < 6; i++) { v[i] = x[lane + i*64]; s += v[i]; }
#pragma unroll
    for (int off = 32; off > 0; off >>= 1) s += __shfl_xor(s, off, 64);
    float mu = s * (1.0f/384.0f);
    float vs = 0.f;
#pragma unroll
    for (int i = 0; i < 6; i++) { float d = v[i]-mu; vs += d*d; }
#pragma unroll
    for (int off = 32; off > 0; off >>= 1) vs += __shfl_xor(vs, off, 64);
    float rstd = 1.0f / sqrtf(vs * (1.0f/384.0f) + 1e-5f);
#pragma unroll
    for (int i = 0; i < 6; i++) {
        int col = lane + i*64;
        float y = (v[i] - mu) * rstd * lng[col] + lnb[col];
        short h, l; split2(y, h, l);
        Xh[(size_t)row * C_ + col] = h;
        Xl[(size_t)row * C_ + col] = l;
    }
}

// ---------------- weight transpose + split-bf16 convert ----------------
__global__ __launch_bounds__(256) void conv_w_kernel(const float* __restrict__ w,
                                                     short* __restrict__ th,
                                                     short* __restrict__ tl,
                                                     int K, int N, int Npad) {
    __shared__ float t[32][33];
    int n0 = blockIdx.x * 32, k0 = blockIdx.y * 32;
    int tx = threadIdx.x & 31, ty = threadIdx.x >> 5;
#pragma unroll
    for (int i = ty; i < 32; i += 8) {
        int k = k0 + i, n = n0 + tx;
        t[i][tx] = (n < N) ? w[(size_t)k * N + n] : 0.f;
    }
    __syncthreads();
#pragma unroll
    for (int i = ty; i < 32; i += 8) {
        int n = n0 + i, k = k0 + tx;
        short h, l; split2(t[tx][i], h, l);
        th[(size_t)n * K + k] = h;
        tl[(size_t)n * K + k] = l;
    }
}

// ---------------- presplit GEMM: 128x128 tile, global_load_lds staging ----------
// A (pre-split planes, M x K) @ B^T (pre-split planes, N x K), bias+relu,
// split-bf16 output planes. Unpadded LDS [128][32] (wave-uniform-base DMA order).
// grid: (chunkM/128, N/128) -- x = row tiles (same-A blocks -> same XCD)
__global__ __launch_bounds__(256) void presplit_gemm128(
    const short* __restrict__ Ahg, const short* __restrict__ Alg,
    const short* __restrict__ BTh, const short* __restrict__ BTl,
    const float* __restrict__ bias,
    short* __restrict__ Ch, short* __restrict__ Cl,
    int K, int ldc)
{
    __shared__ short Ah[128][32], Al[128][32], Bh[128][32], Bl[128][32];
    int tid = threadIdx.x;
    int m0 = blockIdx.x * 128;
    int n0 = blockIdx.y * 128;
    int lane = tid & 63, wv = tid >> 6;
    int wm = (wv & 1) * 64, wn = (wv >> 1) * 64;
    int fm = lane & 15, kg = lane >> 4;

    // staging role: wave wv owns one plane
    const short* gsrc = (wv == 0) ? Ahg : (wv == 1) ? Alg : (wv == 2) ? BTh : BTl;
    short* lbase = (wv == 0) ? &Ah[0][0] : (wv == 1) ? &Al[0][0]
                 : (wv == 2) ? &Bh[0][0] : &Bl[0][0];
    int base = (wv < 2) ? m0 : n0;
    const short* gp = gsrc + (size_t)(base + (lane >> 2)) * K + (lane & 3) * 8;

    f32x4 acc[4][4] = {};

    for (int k0 = 0; k0 < K; k0 += BK) {
#pragma unroll
        for (int c = 0; c < 8; c++)
            GLOAD_LDS(gp + (size_t)(c * 16) * K + k0, lbase + c * 512);
        __syncthreads();

        bf16x8 a_h[4], a_l[4], b_h[4], b_l[4];
#pragma unroll
        for (int i = 0; i < 4; i++) {
            a_h[i] = *(bf16x8*)&Ah[wm + i*16 + fm][kg*8];
            a_l[i] = *(bf16x8*)&Al[wm + i*16 + fm][kg*8];
            b_h[i] = *(bf16x8*)&Bh[wn + i*16 + fm][kg*8];
            b_l[i] = *(bf16x8*)&Bl[wn + i*16 + fm][kg*8];
        }
#pragma unroll
        for (int i = 0; i < 4; i++)
#pragma unroll
            for (int j = 0; j < 4; j++) {
                f32x4 c = acc[i][j];
                c = __builtin_amdgcn_mfma_f32_16x16x32_bf16(a_l[i], b_h[j], c, 0, 0, 0);
                c = __builtin_amdgcn_mfma_f32_16x16x32_bf16(a_h[i], b_l[j], c, 0, 0, 0);
                c = __builtin_amdgcn_mfma_f32_16x16x32_bf16(a_h[i], b_h[j], c, 0, 0, 0);
                acc[i][j] = c;
            }
        __syncthreads();
    }

#pragma unroll
    for (int i = 0; i < 4; i++)
#pragma unroll
        for (int j = 0; j < 4; j++) {
            int col = n0 + wn + j*16 + fm;
            float bs = bias[col];
#pragma unroll
            for (int r = 0; r < 4; r++) {
                int row = m0 + wm + i*16 + kg*4 + r;
                float v = fmaxf(acc[i][j][r] + bs, 0.f);
                short h, l; split2(v, h, l);
                Ch[(size_t)row * ldc + col] = h;
                Cl[(size_t)row * ldc + col] = l;
            }
        }
}

// ---------------- GEMM3 fused: full-K, logits + argmax + mask in-kernel ----------
// grid: (chunkM/128). A tile 128x32 (waves 0-1 hi/lo), B tile 32x32 (waves 2-3).
__global__ __launch_bounds__(256) void gemm3_fused(
    const short* __restrict__ Ahg, const short* __restrict__ Alg,   // H2 planes [M][1024]
    const short* __restrict__ BTh, const short* __restrict__ BTl,   // w3 planes [128][1024]
    const float* __restrict__ b3,
    const int* __restrict__ fixed_mask, const int* __restrict__ seq_t,
    float* __restrict__ out_logits, float* __restrict__ seq_out,
    int* __restrict__ seq_int, int m0c)
{
    __shared__ short Ah[128][32], Al[128][32];
    __shared__ short Bh[32][32], Bl[32][32];
    __shared__ float slog[128][33];
    int tid = threadIdx.x;
    int m0 = blockIdx.x * 128;
    int lane = tid & 63, wv = tid >> 6;
    int wm = wv * 32;
    int fm = lane & 15, kg = lane >> 4;

    const short* gsrc = (wv == 0) ? Ahg : (wv == 1) ? Alg : (wv == 2) ? BTh : BTl;
    short* lbase = (wv == 0) ? &Ah[0][0] : (wv == 1) ? &Al[0][0]
                 : (wv == 2) ? &Bh[0][0] : &Bl[0][0];
    int base = (wv < 2) ? m0 : 0;
    int ncalls = (wv < 2) ? 8 : 2;
    const short* gp = gsrc + (size_t)(base + (lane >> 2)) * H_ + (lane & 3) * 8;

    f32x4 acc[2][2] = {};

    for (int k0 = 0; k0 < H_; k0 += BK) {
        for (int c = 0; c < ncalls; c++)
            GLOAD_LDS(gp + (size_t)(c * 16) * H_ + k0, lbase + c * 512);
        __syncthreads();

        bf16x8 a_h[2], a_l[2], b_h[2], b_l[2];
#pragma unroll
        for (int i = 0; i < 2; i++) {
            a_h[i] = *(bf16x8*)&Ah[wm + i*16 + fm][kg*8];
            a_l[i] = *(bf16x8*)&Al[wm + i*16 + fm][kg*8];
        }
#pragma unroll
        for (int j = 0; j < 2; j++) {
            b_h[j] = *(bf16x8*)&Bh[j*16 + fm][kg*8];
            b_l[j] = *(bf16x8*)&Bl[j*16 + fm][kg*8];
        }
#pragma unroll
        for (int i = 0; i < 2; i++)
#pragma unroll
            for (int j = 0; j < 2; j++) {
                f32x4 c = acc[i][j];
                c = __builtin_amdgcn_mfma_f32_16x16x32_bf16(a_l[i], b_h[j], c, 0, 0, 0);
                c = __builtin_amdgcn_mfma_f32_16x16x32_bf16(a_h[i], b_l[j], c, 0, 0, 0);
                c = __builtin_amdgcn_mfma_f32_16x16x32_bf16(a_h[i], b_h[j], c, 0, 0, 0);
                acc[i][j] = c;
            }
        __syncthreads();
    }

#pragma unroll
    for (int i = 0; i < 2; i++)
#pragma unroll
        for (int j = 0; j < 2; j++)
#pragma unroll
            for (int r = 0; r < 4; r++)
                slog[wm + i*16 + kg*4 + r][j*16 + fm] = acc[i][j][r];
    __syncthreads();

    if (tid < 128) {
        int grow = m0c + m0 + tid;
        float best = -1e30f; int bi = 0;
        float* lg = out_logits + (size_t)grow * NRES;
#pragma unroll
        for (int n = 0; n < NRES; n++) {
            float s = slog[tid][n] + b3[n];
            lg[n] = s;
            if (s > best) { best = s; bi = n; }
        }
        int fmk = fixed_mask[grow];
        int s = fmk ? seq_t[grow] : bi;
        seq_int[grow] = s;
        seq_out[grow] = (float)s;
    }
}

// ---------------- geometry: one thread per (b,n) ----------------
__global__ __launch_bounds__(128) void geom_kernel(
    const float* __restrict__ angles, const float* __restrict__ rigids,
    const int* __restrict__ seq0i, const int* __restrict__ residx,
    const float* __restrict__ dframes, const int* __restrict__ gidx,
    const float* __restrict__ a14m, const float* __restrict__ a37m,
    const float* __restrict__ litp,
    float* __restrict__ out_pred, float* __restrict__ out_final,
    float* __restrict__ out_m14, float* __restrict__ out_m37)
{
    __shared__ float sdf[NTAB*8*16];
    __shared__ int   sgi[NTAB*14];
    __shared__ float sm14[NTAB*14];
    __shared__ float sm37[NTAB*37];
    __shared__ float slit[NTAB*14*3];
    __shared__ float predL[128][43];

    for (int i = threadIdx.x; i < NTAB*128; i += 128) sdf[i] = dframes[i];
    for (int i = threadIdx.x; i < NTAB*14; i += 128) { sgi[i] = gidx[i]; sm14[i] = a14m[i]; }
    for (int i = threadIdx.x; i < NTAB*37; i += 128) sm37[i] = a37m[i];
    for (int i = threadIdx.x; i < NTAB*42; i += 128) slit[i] = litp[i];
    __syncthreads();

    int p = blockIdx.x * 128 + threadIdx.x;
    int s = seq0i[p];

    const float* rg = rigids + (size_t)p * 7;
    float qw = rg[0], qx = rg[1], qy = rg[2], qz = rg[3];
    float tbx = rg[4], tby = rg[5], tbz = rg[6];
    float qn = 1.0f / sqrtf(qw*qw + qx*qx + qy*qy + qz*qz + 1e-8f);
    qw *= qn; qx *= qn; qy *= qn; qz *= qn;
    float rb[9];
    rb[0] = 1.f - 2.f*(qy*qy + qz*qz); rb[1] = 2.f*(qx*qy - qw*qz); rb[2] = 2.f*(qx*qz + qw*qy);
    rb[3] = 2.f*(qx*qy + qw*qz); rb[4] = 1.f - 2.f*(qx*qx + qz*qz); rb[5] = 2.f*(qy*qz - qw*qx);
    rb[6] = 2.f*(qx*qz - qw*qy); rb[7] = 2.f*(qy*qz + qw*qx); rb[8] = 1.f - 2.f*(qx*qx + qy*qy);

    float fr[8][9], ft[8][3];
    const float* ang = angles + (size_t)p * 14;
#pragma unroll
    for (int g = 0; g < 8; g++) {
        const float* df = &sdf[(s*8 + g)*16];
        float c, sn;
        if (g == 0) { c = 1.f; sn = 0.f; }
        else { sn = ang[(g-1)*2 + 0]; c = ang[(g-1)*2 + 1]; }
#pragma unroll
        for (int i = 0; i < 3; i++) {
            float d0 = df[i*4+0], d1 = df[i*4+1], d2 = df[i*4+2];
            fr[g][i*3+0] = d0;
            fr[g][i*3+1] = d1*c + d2*sn;
            fr[g][i*3+2] = d2*c - d1*sn;
            ft[g][i] = df[i*4+3];
        }
    }
#pragma unroll
    for (int g = 5; g <= 7; g++) {
        float r[9], t[3];
        const float* r1 = fr[g-1];
        const float* t1 = ft[g-1];
#pragma unroll
        for (int i = 0; i < 3; i++) {
#pragma unroll
            for (int j = 0; j < 3; j++)
                r[i*3+j] = r1[i*3+0]*fr[g][0*3+j] + r1[i*3+1]*fr[g][1*3+j] + r1[i*3+2]*fr[g][2*3+j];
            t[i] = r1[i*3+0]*ft[g][0] + r1[i*3+1]*ft[g][1] + r1[i*3+2]*ft[g][2] + t1[i];
        }
#pragma unroll
        for (int i = 0; i < 9; i++) fr[g][i] = r[i];
#pragma unroll
        for (int i = 0; i < 3; i++) ft[g][i] = t[i];
    }
#pragma unroll
    for (int g = 0; g < 8; g++) {
        float r[9], t[3];
#pragma unroll
        for (int i = 0; i < 3; i++) {
#pragma unroll
            for (int j = 0; j < 3; j++)
                r[i*3+j] = rb[i*3+0]*fr[g][0*3+j] + rb[i*3+1]*fr[g][1*3+j] + rb[i*3+2]*fr[g][2*3+j];
            t[i] = rb[i*3+0]*ft[g][0] + rb[i*3+1]*ft[g][1] + rb[i*3+2]*ft[g][2];
        }
#pragma unroll
        for (int i = 0; i < 9; i++) fr[g][i] = r[i];
        ft[g][0]=t[0]+tbx; ft[g][1]=t[1]+tby; ft[g][2]=t[2]+tbz;
    }
#pragma unroll
    for (int g = 0; g < 8; g++) {
#pragma unroll
        for (int a = 0; a < 14; a++) {
            if (sgi[s*14 + a] == g) {
                float m  = sm14[s*14 + a];
                float lx = slit[(s*14 + a)*3 + 0];
                float ly = slit[(s*14 + a)*3 + 1];
                float lz = slit[(s*14 + a)*3 + 2];
                float px = (fr[g][0]*lx + fr[g][1]*ly + fr[g][2]*lz + ft[g][0]) * m;
                float py = (fr[g][3]*lx + fr[g][4]*ly + fr[g][5]*lz + ft[g][1]) * m;
                float pz = (fr[g][6]*lx + fr[g][7]*ly + fr[g][8]*lz + ft[g][2]) * m;
                predL[threadIdx.x][a*3+0] = px;
                predL[threadIdx.x][a*3+1] = py;
                predL[threadIdx.x][a*3+2] = pz;
                out_pred[((size_t)p*14 + a)*3 + 0] = px;
                out_pred[((size_t)p*14 + a)*3 + 1] = py;
                out_pred[((size_t)p*14 + a)*3 + 2] = pz;
            }
        }
    }
#pragma unroll
    for (int a = 0; a < 14; a++) out_m14[(size_t)p*14 + a] = sm14[s*14 + a];

    const int* idx = residx + (size_t)p * 37;
#pragma unroll
    for (int a = 0; a < 37; a++) {
        int id = idx[a];
        out_final[((size_t)p*37 + a)*3 + 0] = predL[threadIdx.x][id*3+0];
        out_final[((size_t)p*37 + a)*3 + 1] = predL[threadIdx.x][id*3+1];
        out_final[((size_t)p*37 + a)*3 + 2] = predL[threadIdx.x][id*3+2];
        out_m37[(size_t)p*37 + a] = sm37[s*37 + a];
    }
}

extern "C" void kernel_launch(void* const* d_in, const int* in_sizes, int n_in,
                              void* d_out, int out_size, void* d_ws, size_t ws_size,
                              hipStream_t stream) {
    const float* act        = (const float*)d_in[0];
    const float* angles     = (const float*)d_in[1];
    const float* rigids     = (const float*)d_in[2];
    const int*   fixed_mask = (const int*)d_in[3];
    const int*   seq_t      = (const int*)d_in[4];
    const int*   residx     = (const int*)d_in[5];
    const float* lng        = (const float*)d_in[6];
    const float* lnb        = (const float*)d_in[7];
    const float* w1         = (const float*)d_in[8];
    const float* b1         = (const float*)d_in[9];
    const float* w2         = (const float*)d_in[10];
    const float* b2         = (const float*)d_in[11];
    const float* w3         = (const float*)d_in[12];
    const float* b3         = (const float*)d_in[13];
    const float* dfr        = (const float*)d_in[14];
    const int*   gidx       = (const int*)d_in[15];
    const float* a14m       = (const float*)d_in[16];
    const float* a37m       = (const float*)d_in[17];
    const float* litp       = (const float*)d_in[18];

    float* out        = (float*)d_out;
    float* out_logits = out;
    float* out_seq    = out_logits + (size_t)M_TOTAL * NRES;
    float* out_pred   = out_seq    + (size_t)M_TOTAL;
    float* out_final  = out_pred   + (size_t)M_TOTAL * 42;
    float* out_m14    = out_final  + (size_t)M_TOTAL * 111;
    float* out_m37    = out_m14    + (size_t)M_TOTAL * 14;

    char* wsp = (char*)d_ws;
    int*   seq0i = (int*)wsp;   wsp += (size_t)M_TOTAL * sizeof(int);
    short* w1h   = (short*)wsp; wsp += (size_t)H_ * C_ * sizeof(short);
    short* w1l   = (short*)wsp; wsp += (size_t)H_ * C_ * sizeof(short);
    short* w2h   = (short*)wsp; wsp += (size_t)H_ * H_ * sizeof(short);
    short* w2l   = (short*)wsp; wsp += (size_t)H_ * H_ * sizeof(short);
    short* w3h   = (short*)wsp; wsp += (size_t)128 * H_ * sizeof(short);
    short* w3l   = (short*)wsp; wsp += (size_t)128 * H_ * sizeof(short);
    short* Xh    = (short*)wsp; wsp += (size_t)M_TOTAL * C_ * sizeof(short);
    short* Xl    = (short*)wsp; wsp += (size_t)M_TOTAL * C_ * sizeof(short);

    size_t fixed_bytes = (size_t)(wsp - (char*)d_ws);
    size_t per_row = 4ull * H_ * sizeof(short);   // H1h/H1l/H2h/H2l
    size_t avail = ws_size - fixed_bytes;
    int chunkM = 4096;
    if (avail >= (size_t)M_TOTAL * per_row)      chunkM = M_TOTAL;
    else if (avail >= 16384ull * per_row)        chunkM = 16384;
    else if (avail >= 8192ull * per_row)         chunkM = 8192;

    short* H1h = (short*)wsp; wsp += (size_t)chunkM * H_ * sizeof(short);
    short* H1l = (short*)wsp; wsp += (size_t)chunkM * H_ * sizeof(short);
    short* H2h = (short*)wsp; wsp += (size_t)chunkM * H_ * sizeof(short);
    short* H2l = (short*)wsp;

    conv_w_kernel<<<dim3(H_/32, C_/32), 256, 0, stream>>>(w1, w1h, w1l, C_, H_, H_);
    conv_w_kernel<<<dim3(H_/32, H_/32), 256, 0, stream>>>(w2, w2h, w2l, H_, H_, H_);
    conv_w_kernel<<<dim3(128/32, H_/32), 256, 0, stream>>>(w3, w3h, w3l, H_, NRES, 128);

    ln_split_kernel<<<M_TOTAL/4, 256, 0, stream>>>(act, lng, lnb, Xh, Xl);

    for (int c = 0; c < M_TOTAL / chunkM; c++) {
        int m0 = c * chunkM;
        // GEMM1: LN'd act planes @ w1 (K=384)
        presplit_gemm128<<<dim3(chunkM/128, H_/128), 256, 0, stream>>>(
            Xh + (size_t)m0 * C_, Xl + (size_t)m0 * C_, w1h, w1l, b1, H1h, H1l, C_, H_);
        // GEMM2: H1 @ w2 (K=1024)
        presplit_gemm128<<<dim3(chunkM/128, H_/128), 256, 0, stream>>>(
            H1h, H1l, w2h, w2l, b2, H2h, H2l, H_, H_);
        // GEMM3 + logits + argmax + mask, fused
        gemm3_fused<<<chunkM/128, 256, 0, stream>>>(H2h, H2l, w3h, w3l, b3,
                                                    fixed_mask, seq_t,
                                                    out_logits, out_seq, seq0i, m0);
    }

    geom_kernel<<<M_TOTAL/128, 128, 0, stream>>>(angles, rigids, seq0i, residx,
                                                 dfr, gidx, a14m, a37m, litp,
                                                 out_pred, out_final, out_m14, out_m37);
}

// Round 8
// 514.484 us; speedup vs baseline: 4.1530x; 1.0480x over previous
//
#include <hip/hip_runtime.h>
#include <math.h>

#define B_ 32
#define N_ 1024
#define C_ 384
#define H_ 1024
#define NRES 20
#define NTAB 21
#define M_TOTAL (B_*N_)   // 32768
#define BK 32

typedef __attribute__((ext_vector_type(8))) short bf16x8;
typedef __attribute__((ext_vector_type(4))) float f32x4;

#define GLOAD_LDS(gptr, lptr) \
    __builtin_amdgcn_global_load_lds( \
        (const __attribute__((address_space(1))) void*)(gptr), \
        (__attribute__((address_space(3))) void*)(lptr), 16, 0, 0)

__device__ inline short bf16_rne(float v) {
    unsigned u = __float_as_uint(v);
    unsigned r = u + 0x7fffu + ((u >> 16) & 1u);
    return (short)(r >> 16);
}
// v ~= hi + lo, each bf16 (RNE). ~16 mantissa bits captured.
__device__ inline void split2(float v, short& h, short& l) {
    unsigned u = __float_as_uint(v);
    unsigned r = (u + 0x7fffu + ((u >> 16) & 1u)) & 0xffff0000u;
    h = (short)(r >> 16);
    l = bf16_rne(v - __uint_as_float(r));
}

// ---------------- LN + split: one wave per row, full M ----------------
__global__ __launch_bounds__(256) void ln_split_kernel(const float* __restrict__ act,
                                                       const float* __restrict__ lng,
                                                       const float* __restrict__ lnb,
                                                       short* __restrict__ Xh,
                                                       short* __restrict__ Xl) {
    int wave = threadIdx.x >> 6;
    int lane = threadIdx.x & 63;
    int row  = blockIdx.x * 4 + wave;
    const float* x = act + (size_t)row * C_;
    float v[6];
    float s = 0.f;
#pragma unroll
    for (int i = 0; i < 6; i++) { v[i] = x[lane + i*64]; s += v[i]; }
#pragma unroll
    for (int off = 32; off > 0; off >>= 1) s += __shfl_xor(s, off, 64);
    float mu = s * (1.0f/384.0f);
    float vs = 0.f;
#pragma unroll
    for (int i = 0; i < 6; i++) { float d = v[i]-mu; vs += d*d; }
#pragma unroll
    for (int off = 32; off > 0; off >>= 1) vs += __shfl_xor(vs, off, 64);
    float rstd = 1.0f / sqrtf(vs * (1.0f/384.0f) + 1e-5f);
#pragma unroll
    for (int i = 0; i < 6; i++) {
        int col = lane + i*64;
        float y = (v[i] - mu) * rstd * lng[col] + lnb[col];
        short h, l; split2(y, h, l);
        Xh[(size_t)row * C_ + col] = h;
        Xl[(size_t)row * C_ + col] = l;
    }
}

// ---------------- weight transpose + split-bf16 convert ----------------
__global__ __launch_bounds__(256) void conv_w_kernel(const float* __restrict__ w,
                                                     short* __restrict__ th,
                                                     short* __restrict__ tl,
                                                     int K, int N, int Npad) {
    __shared__ float t[32][33];
    int n0 = blockIdx.x * 32, k0 = blockIdx.y * 32;
    int tx = threadIdx.x & 31, ty = threadIdx.x >> 5;
#pragma unroll
    for (int i = ty; i < 32; i += 8) {
        int k = k0 + i, n = n0 + tx;
        t[i][tx] = (n < N) ? w[(size_t)k * N + n] : 0.f;
    }
    __syncthreads();
#pragma unroll
    for (int i = ty; i < 32; i += 8) {
        int n = n0 + i, k = k0 + tx;
        short h, l; split2(t[tx][i], h, l);
        th[(size_t)n * K + k] = h;
        tl[(size_t)n * K + k] = l;
    }
}

// ---------------- presplit GEMM: 128x128 tile, global_load_lds + XOR swizzle ------
// LDS[row][cb] holds global[row][cb ^ ((row>>1)&3)] (col-blocks of 8 bf16).
// DMA stays lane-contiguous; reads use the swizzled col-block -> conflict-free.
// grid: (chunkM/128, N/128) -- x = row tiles (same-A blocks -> same XCD)
__global__ __launch_bounds__(256) void presplit_gemm128(
    const short* __restrict__ Ahg, const short* __restrict__ Alg,
    const short* __restrict__ BTh, const short* __restrict__ BTl,
    const float* __restrict__ bias,
    short* __restrict__ Ch, short* __restrict__ Cl,
    int K, int ldc)
{
    __shared__ short Ah[128][32], Al[128][32], Bh[128][32], Bl[128][32];
    int tid = threadIdx.x;
    int m0 = blockIdx.x * 128;
    int n0 = blockIdx.y * 128;
    int lane = tid & 63, wv = tid >> 6;
    int wm = (wv & 1) * 64, wn = (wv >> 1) * 64;
    int fm = lane & 15, kg = lane >> 4;

    // staging role: wave wv owns one plane
    const short* gsrc = (wv == 0) ? Ahg : (wv == 1) ? Alg : (wv == 2) ? BTh : BTl;
    short* lbase = (wv == 0) ? &Ah[0][0] : (wv == 1) ? &Al[0][0]
                 : (wv == 2) ? &Bh[0][0] : &Bl[0][0];
    int base = (wv < 2) ? m0 : n0;
    // lane l -> LDS slot (row16=l>>2, cb=l&3); fetch global cb ^ swz(row16)
    int swcb = (lane & 3) ^ ((lane >> 3) & 3);
    const short* gp = gsrc + (size_t)(base + (lane >> 2)) * K + swcb * 8;

    // swizzled read col-blocks (in shorts), one per fragment row
    int sa[4], sb[4];
#pragma unroll
    for (int i = 0; i < 4; i++) {
        int ra = wm + i*16 + fm;
        int rb = wn + i*16 + fm;
        sa[i] = (kg ^ ((ra >> 1) & 3)) * 8;
        sb[i] = (kg ^ ((rb >> 1) & 3)) * 8;
    }

    f32x4 acc[4][4] = {};

    for (int k0 = 0; k0 < K; k0 += BK) {
#pragma unroll
        for (int c = 0; c < 8; c++)
            GLOAD_LDS(gp + (size_t)(c * 16) * K + k0, lbase + c * 512);
        __syncthreads();

        bf16x8 a_h[4], a_l[4], b_h[4], b_l[4];
#pragma unroll
        for (int i = 0; i < 4; i++) {
            a_h[i] = *(bf16x8*)&Ah[wm + i*16 + fm][sa[i]];
            a_l[i] = *(bf16x8*)&Al[wm + i*16 + fm][sa[i]];
            b_h[i] = *(bf16x8*)&Bh[wn + i*16 + fm][sb[i]];
            b_l[i] = *(bf16x8*)&Bl[wn + i*16 + fm][sb[i]];
        }
#pragma unroll
        for (int i = 0; i < 4; i++)
#pragma unroll
            for (int j = 0; j < 4; j++) {
                f32x4 c = acc[i][j];
                c = __builtin_amdgcn_mfma_f32_16x16x32_bf16(a_l[i], b_h[j], c, 0, 0, 0);
                c = __builtin_amdgcn_mfma_f32_16x16x32_bf16(a_h[i], b_l[j], c, 0, 0, 0);
                c = __builtin_amdgcn_mfma_f32_16x16x32_bf16(a_h[i], b_h[j], c, 0, 0, 0);
                acc[i][j] = c;
            }
        __syncthreads();
    }

#pragma unroll
    for (int i = 0; i < 4; i++)
#pragma unroll
        for (int j = 0; j < 4; j++) {
            int col = n0 + wn + j*16 + fm;
            float bs = bias[col];
#pragma unroll
            for (int r = 0; r < 4; r++) {
                int row = m0 + wm + i*16 + kg*4 + r;
                float v = fmaxf(acc[i][j][r] + bs, 0.f);
                short h, l; split2(v, h, l);
                Ch[(size_t)row * ldc + col] = h;
                Cl[(size_t)row * ldc + col] = l;
            }
        }
}

// ---------------- GEMM3 fused: 64-row blocks, full-K, logits+argmax in-kernel ----
// grid: (chunkM/64). Waves 0/1 stage A hi/lo (4 DMA calls), waves 2/3 stage B (2).
__global__ __launch_bounds__(256) void gemm3_fused(
    const short* __restrict__ Ahg, const short* __restrict__ Alg,   // H2 planes [M][1024]
    const short* __restrict__ BTh, const short* __restrict__ BTl,   // w3 planes [128][1024]
    const float* __restrict__ b3,
    const int* __restrict__ fixed_mask, const int* __restrict__ seq_t,
    float* __restrict__ out_logits, float* __restrict__ seq_out,
    int* __restrict__ seq_int, int m0c)
{
    __shared__ short Ah[64][32], Al[64][32];
    __shared__ short Bh[32][32], Bl[32][32];
    __shared__ float slog[64][33];
    int tid = threadIdx.x;
    int m0 = blockIdx.x * 64;
    int lane = tid & 63, wv = tid >> 6;
    int wm = wv * 16;          // each wave computes 16 rows
    int fm = lane & 15, kg = lane >> 4;

    const short* gsrc = (wv == 0) ? Ahg : (wv == 1) ? Alg : (wv == 2) ? BTh : BTl;
    short* lbase = (wv == 0) ? &Ah[0][0] : (wv == 1) ? &Al[0][0]
                 : (wv == 2) ? &Bh[0][0] : &Bl[0][0];
    int base = (wv < 2) ? m0 : 0;
    int swcb = (lane & 3) ^ ((lane >> 3) & 3);
    const short* gp = gsrc + (size_t)(base + (lane >> 2)) * H_ + swcb * 8;

    int saz = (kg ^ (((wm + fm) >> 1) & 3)) * 8;
    int sbz[2];
#pragma unroll
    for (int j = 0; j < 2; j++) sbz[j] = (kg ^ (((j*16 + fm) >> 1) & 3)) * 8;

    f32x4 acc[2] = {};

    for (int k0 = 0; k0 < H_; k0 += BK) {
        if (wv < 2) {
#pragma unroll
            for (int c = 0; c < 4; c++)
                GLOAD_LDS(gp + (size_t)(c * 16) * H_ + k0, lbase + c * 512);
        } else {
#pragma unroll
            for (int c = 0; c < 2; c++)
                GLOAD_LDS(gp + (size_t)(c * 16) * H_ + k0, lbase + c * 512);
        }
        __syncthreads();

        bf16x8 a_h = *(bf16x8*)&Ah[wm + fm][saz];
        bf16x8 a_l = *(bf16x8*)&Al[wm + fm][saz];
        bf16x8 b_h[2], b_l[2];
#pragma unroll
        for (int j = 0; j < 2; j++) {
            b_h[j] = *(bf16x8*)&Bh[j*16 + fm][sbz[j]];
            b_l[j] = *(bf16x8*)&Bl[j*16 + fm][sbz[j]];
        }
#pragma unroll
        for (int j = 0; j < 2; j++) {
            f32x4 c = acc[j];
            c = __builtin_amdgcn_mfma_f32_16x16x32_bf16(a_l, b_h[j], c, 0, 0, 0);
            c = __builtin_amdgcn_mfma_f32_16x16x32_bf16(a_h, b_l[j], c, 0, 0, 0);
            c = __builtin_amdgcn_mfma_f32_16x16x32_bf16(a_h, b_h[j], c, 0, 0, 0);
            acc[j] = c;
        }
        __syncthreads();
    }

#pragma unroll
    for (int j = 0; j < 2; j++)
#pragma unroll
        for (int r = 0; r < 4; r++)
            slog[wm + kg*4 + r][j*16 + fm] = acc[j][r];
    __syncthreads();

    if (tid < 64) {
        int grow = m0c + m0 + tid;
        float best = -1e30f; int bi = 0;
        float* lg = out_logits + (size_t)grow * NRES;
#pragma unroll
        for (int n = 0; n < NRES; n++) {
            float s = slog[tid][n] + b3[n];
            lg[n] = s;
            if (s > best) { best = s; bi = n; }
        }
        int fmk = fixed_mask[grow];
        int s = fmk ? seq_t[grow] : bi;
        seq_int[grow] = s;
        seq_out[grow] = (float)s;
    }
}

// ---------------- geometry: one thread per (b,n) ----------------
__global__ __launch_bounds__(128) void geom_kernel(
    const float* __restrict__ angles, const float* __restrict__ rigids,
    const int* __restrict__ seq0i, const int* __restrict__ residx,
    const float* __restrict__ dframes, const int* __restrict__ gidx,
    const float* __restrict__ a14m, const float* __restrict__ a37m,
    const float* __restrict__ litp,
    float* __restrict__ out_pred, float* __restrict__ out_final,
    float* __restrict__ out_m14, float* __restrict__ out_m37)
{
    __shared__ float sdf[NTAB*8*16];
    __shared__ int   sgi[NTAB*14];
    __shared__ float sm14[NTAB*14];
    __shared__ float sm37[NTAB*37];
    __shared__ float slit[NTAB*14*3];
    __shared__ float predL[128][43];

    for (int i = threadIdx.x; i < NTAB*128; i += 128) sdf[i] = dframes[i];
    for (int i = threadIdx.x; i < NTAB*14; i += 128) { sgi[i] = gidx[i]; sm14[i] = a14m[i]; }
    for (int i = threadIdx.x; i < NTAB*37; i += 128) sm37[i] = a37m[i];
    for (int i = threadIdx.x; i < NTAB*42; i += 128) slit[i] = litp[i];
    __syncthreads();

    int p = blockIdx.x * 128 + threadIdx.x;
    int s = seq0i[p];

    const float* rg = rigids + (size_t)p * 7;
    float qw = rg[0], qx = rg[1], qy = rg[2], qz = rg[3];
    float tbx = rg[4], tby = rg[5], tbz = rg[6];
    float qn = 1.0f / sqrtf(qw*qw + qx*qx + qy*qy + qz*qz + 1e-8f);
    qw *= qn; qx *= qn; qy *= qn; qz *= qn;
    float rb[9];
    rb[0] = 1.f - 2.f*(qy*qy + qz*qz); rb[1] = 2.f*(qx*qy - qw*qz); rb[2] = 2.f*(qx*qz + qw*qy);
    rb[3] = 2.f*(qx*qy + qw*qz); rb[4] = 1.f - 2.f*(qx*qx + qz*qz); rb[5] = 2.f*(qy*qz - qw*qx);
    rb[6] = 2.f*(qx*qz - qw*qy); rb[7] = 2.f*(qy*qz + qw*qx); rb[8] = 1.f - 2.f*(qx*qx + qy*qy);

    float fr[8][9], ft[8][3];
    const float* ang = angles + (size_t)p * 14;
#pragma unroll
    for (int g = 0; g < 8; g++) {
        const float* df = &sdf[(s*8 + g)*16];
        float c, sn;
        if (g == 0) { c = 1.f; sn = 0.f; }
        else { sn = ang[(g-1)*2 + 0]; c = ang[(g-1)*2 + 1]; }
#pragma unroll
        for (int i = 0; i < 3; i++) {
            float d0 = df[i*4+0], d1 = df[i*4+1], d2 = df[i*4+2];
            fr[g][i*3+0] = d0;
            fr[g][i*3+1] = d1*c + d2*sn;
            fr[g][i*3+2] = d2*c - d1*sn;
            ft[g][i] = df[i*4+3];
        }
    }
#pragma unroll
    for (int g = 5; g <= 7; g++) {
        float r[9], t[3];
        const float* r1 = fr[g-1];
        const float* t1 = ft[g-1];
#pragma unroll
        for (int i = 0; i < 3; i++) {
#pragma unroll
            for (int j = 0; j < 3; j++)
                r[i*3+j] = r1[i*3+0]*fr[g][0*3+j] + r1[i*3+1]*fr[g][1*3+j] + r1[i*3+2]*fr[g][2*3+j];
            t[i] = r1[i*3+0]*ft[g][0] + r1[i*3+1]*ft[g][1] + r1[i*3+2]*ft[g][2] + t1[i];
        }
#pragma unroll
        for (int i = 0; i < 9; i++) fr[g][i] = r[i];
#pragma unroll
        for (int i = 0; i < 3; i++) ft[g][i] = t[i];
    }
#pragma unroll
    for (int g = 0; g < 8; g++) {
        float r[9], t[3];
#pragma unroll
        for (int i = 0; i < 3; i++) {
#pragma unroll
            for (int j = 0; j < 3; j++)
                r[i*3+j] = rb[i*3+0]*fr[g][0*3+j] + rb[i*3+1]*fr[g][1*3+j] + rb[i*3+2]*fr[g][2*3+j];
            t[i] = rb[i*3+0]*ft[g][0] + rb[i*3+1]*ft[g][1] + rb[i*3+2]*ft[g][2];
        }
#pragma unroll
        for (int i = 0; i < 9; i++) fr[g][i] = r[i];
        ft[g][0]=t[0]+tbx; ft[g][1]=t[1]+tby; ft[g][2]=t[2]+tbz;
    }
#pragma unroll
    for (int g = 0; g < 8; g++) {
#pragma unroll
        for (int a = 0; a < 14; a++) {
            if (sgi[s*14 + a] == g) {
                float m  = sm14[s*14 + a];
                float lx = slit[(s*14 + a)*3 + 0];
                float ly = slit[(s*14 + a)*3 + 1];
                float lz = slit[(s*14 + a)*3 + 2];
                float px = (fr[g][0]*lx + fr[g][1]*ly + fr[g][2]*lz + ft[g][0]) * m;
                float py = (fr[g][3]*lx + fr[g][4]*ly + fr[g][5]*lz + ft[g][1]) * m;
                float pz = (fr[g][6]*lx + fr[g][7]*ly + fr[g][8]*lz + ft[g][2]) * m;
                predL[threadIdx.x][a*3+0] = px;
                predL[threadIdx.x][a*3+1] = py;
                predL[threadIdx.x][a*3+2] = pz;
                out_pred[((size_t)p*14 + a)*3 + 0] = px;
                out_pred[((size_t)p*14 + a)*3 + 1] = py;
                out_pred[((size_t)p*14 + a)*3 + 2] = pz;
            }
        }
    }
#pragma unroll
    for (int a = 0; a < 14; a++) out_m14[(size_t)p*14 + a] = sm14[s*14 + a];

    const int* idx = residx + (size_t)p * 37;
#pragma unroll
    for (int a = 0; a < 37; a++) {
        int id = idx[a];
        out_final[((size_t)p*37 + a)*3 + 0] = predL[threadIdx.x][id*3+0];
        out_final[((size_t)p*37 + a)*3 + 1] = predL[threadIdx.x][id*3+1];
        out_final[((size_t)p*37 + a)*3 + 2] = predL[threadIdx.x][id*3+2];
        out_m37[(size_t)p*37 + a] = sm37[s*37 + a];
    }
}

extern "C" void kernel_launch(void* const* d_in, const int* in_sizes, int n_in,
                              void* d_out, int out_size, void* d_ws, size_t ws_size,
                              hipStream_t stream) {
    const float* act        = (const float*)d_in[0];
    const float* angles     = (const float*)d_in[1];
    const float* rigids     = (const float*)d_in[2];
    const int*   fixed_mask = (const int*)d_in[3];
    const int*   seq_t      = (const int*)d_in[4];
    const int*   residx     = (const int*)d_in[5];
    const float* lng        = (const float*)d_in[6];
    const float* lnb        = (const float*)d_in[7];
    const float* w1         = (const float*)d_in[8];
    const float* b1         = (const float*)d_in[9];
    const float* w2         = (const float*)d_in[10];
    const float* b2         = (const float*)d_in[11];
    const float* w3         = (const float*)d_in[12];
    const float* b3         = (const float*)d_in[13];
    const float* dfr        = (const float*)d_in[14];
    const int*   gidx       = (const int*)d_in[15];
    const float* a14m       = (const float*)d_in[16];
    const float* a37m       = (const float*)d_in[17];
    const float* litp       = (const float*)d_in[18];

    float* out        = (float*)d_out;
    float* out_logits = out;
    float* out_seq    = out_logits + (size_t)M_TOTAL * NRES;
    float* out_pred   = out_seq    + (size_t)M_TOTAL;
    float* out_final  = out_pred   + (size_t)M_TOTAL * 42;
    float* out_m14    = out_final  + (size_t)M_TOTAL * 111;
    float* out_m37    = out_m14    + (size_t)M_TOTAL * 14;

    char* wsp = (char*)d_ws;
    int*   seq0i = (int*)wsp;   wsp += (size_t)M_TOTAL * sizeof(int);
    short* w1h   = (short*)wsp; wsp += (size_t)H_ * C_ * sizeof(short);
    short* w1l   = (short*)wsp; wsp += (size_t)H_ * C_ * sizeof(short);
    short* w2h   = (short*)wsp; wsp += (size_t)H_ * H_ * sizeof(short);
    short* w2l   = (short*)wsp; wsp += (size_t)H_ * H_ * sizeof(short);
    short* w3h   = (short*)wsp; wsp += (size_t)128 * H_ * sizeof(short);
    short* w3l   = (short*)wsp; wsp += (size_t)128 * H_ * sizeof(short);
    short* Xh    = (short*)wsp; wsp += (size_t)M_TOTAL * C_ * sizeof(short);
    short* Xl    = (short*)wsp; wsp += (size_t)M_TOTAL * C_ * sizeof(short);

    size_t fixed_bytes = (size_t)(wsp - (char*)d_ws);
    size_t per_row = 4ull * H_ * sizeof(short);   // H1h/H1l/H2h/H2l
    size_t avail = ws_size - fixed_bytes;
    int chunkM = 4096;
    if (avail >= (size_t)M_TOTAL * per_row)      chunkM = M_TOTAL;
    else if (avail >= 16384ull * per_row)        chunkM = 16384;
    else if (avail >= 8192ull * per_row)         chunkM = 8192;

    short* H1h = (short*)wsp; wsp += (size_t)chunkM * H_ * sizeof(short);
    short* H1l = (short*)wsp; wsp += (size_t)chunkM * H_ * sizeof(short);
    short* H2h = (short*)wsp; wsp += (size_t)chunkM * H_ * sizeof(short);
    short* H2l = (short*)wsp;

    conv_w_kernel<<<dim3(H_/32, C_/32), 256, 0, stream>>>(w1, w1h, w1l, C_, H_, H_);
    conv_w_kernel<<<dim3(H_/32, H_/32), 256, 0, stream>>>(w2, w2h, w2l, H_, H_, H_);
    conv_w_kernel<<<dim3(128/32, H_/32), 256, 0, stream>>>(w3, w3h, w3l, H_, NRES, 128);

    ln_split_kernel<<<M_TOTAL/4, 256, 0, stream>>>(act, lng, lnb, Xh, Xl);

    for (int c = 0; c < M_TOTAL / chunkM; c++) {
        int m0 = c * chunkM;
        // GEMM1: LN'd act planes @ w1 (K=384)
        presplit_gemm128<<<dim3(chunkM/128, H_/128), 256, 0, stream>>>(
            Xh + (size_t)m0 * C_, Xl + (size_t)m0 * C_, w1h, w1l, b1, H1h, H1l, C_, H_);
        // GEMM2: H1 @ w2 (K=1024)
        presplit_gemm128<<<dim3(chunkM/128, H_/128), 256, 0, stream>>>(
            H1h, H1l, w2h, w2l, b2, H2h, H2l, H_, H_);
        // GEMM3 + logits + argmax + mask, fused (64-row blocks)
        gemm3_fused<<<chunkM/64, 256, 0, stream>>>(H2h, H2l, w3h, w3l, b3,
                                                   fixed_mask, seq_t,
                                                   out_logits, out_seq, seq0i, m0);
    }

    geom_kernel<<<M_TOTAL/128, 128, 0, stream>>>(angles, rigids, seq0i, residx,
                                                 dfr, gidx, a14m, a37m, litp,
                                                 out_pred, out_final, out_m14, out_m37);
}